// Round 2
// baseline (1138.950 us; speedup 1.0000x reference)
//
#include <hip/hip_runtime.h>
#include <float.h>

#define K_DIM 256
#define HW1 1024
#define NROWS 16384
#define NCODES 8192

// ---------------- kernel 1: A[n] = ||z_row||^2 with numpy pairwise order ----
// Replicates np.sum(x**2) for n=256: two 128-blocks, each 8 accumulators
// striding 8 over 16 serial terms, combined ((r0+r1)+(r2+r3))+((r4+r5)+(r6+r7)),
// then left+right. asm barrier stops v*v fusing into the add (np rounds twice).
__global__ void k_znorm(const float* __restrict__ z, float* __restrict__ zn) {
    int n = blockIdx.x * 256 + threadIdx.x;
    int b = n >> 10;
    int hw = n & 1023;
    const float* p = z + b * (K_DIM * HW1) + hw;  // element k at p[k*1024]
    float half[2];
#pragma unroll
    for (int h = 0; h < 2; h++) {
        float r[8];
#pragma unroll
        for (int j = 0; j < 8; j++) {
            float v = p[(h * 128 + j) * HW1];
            float s = v * v;
            asm volatile("" : "+v"(s));
            r[j] = s;
        }
        for (int i = 8; i < 128; i += 8) {
#pragma unroll
            for (int j = 0; j < 8; j++) {
                float v = p[(h * 128 + i + j) * HW1];
                float s = v * v;
                asm volatile("" : "+v"(s));
                r[j] += s;
            }
        }
        half[h] = ((r[0] + r[1]) + (r[2] + r[3])) + ((r[4] + r[5]) + (r[6] + r[7]));
    }
    zn[n] = half[0] + half[1];
}

// ---------------- kernel 2: distance GEMM + per-row argmin ----------------
// grid (128 row-tiles, 64 code-tiles), block 256 (16x16), tile 128x128, K-chunk 64
// distance = fl(A_row - 2*dot)  -- matches np's fp32 quantization; ||e||^2
// provably vanishes in fl(A+B) since B < ulp(A)/2.
__global__ __launch_bounds__(256, 2) void k_dist(
    const float* __restrict__ z, const float* __restrict__ emb,
    const float* __restrict__ zn, unsigned long long* __restrict__ best) {
    __shared__ float As[64][128];  // [k][row]
    __shared__ float Bs[64][128];  // [k][code], cols xor-swizzled by (k&28)

    const int tid = threadIdx.x;
    const int tx = tid & 15;
    const int ty = tid >> 4;
    const int row0 = blockIdx.x * 128;
    const int c0 = blockIdx.y * 128;
    const int bb = row0 >> 10;     // 128 consecutive rows stay within one b
    const int hw0 = row0 & 1023;
    const float* zb = z + bb * (K_DIM * HW1) + hw0;

    float acc[8][8];
#pragma unroll
    for (int i = 0; i < 8; i++)
#pragma unroll
        for (int j = 0; j < 8; j++) acc[i][j] = 0.f;

    for (int k0 = 0; k0 < K_DIM; k0 += 64) {
        // A tile: z_flat[row][k] = z[b][k][hw]; for fixed k, rows are contiguous
#pragma unroll
        for (int i = 0; i < 8; i++) {
            int fid = tid + i * 256;
            int kk = fid >> 5;
            int r4 = (fid & 31) << 2;
            *(float4*)(&As[kk][r4]) = *(const float4*)(zb + (k0 + kk) * HW1 + r4);
        }
        // B tile: transpose emb rows into [k][code] with xor swizzle (4-float grain)
#pragma unroll
        for (int i = 0; i < 8; i++) {
            int fid = tid + i * 256;
            int cc = fid >> 4;
            int k4 = (fid & 15) << 2;
            int sm = (fid & 7) << 2;  // = ((k4>>2)&7)<<2
            float4 v = *(const float4*)(emb + (c0 + cc) * K_DIM + k0 + k4);
            int col = cc ^ sm;
            Bs[k4 + 0][col] = v.x;
            Bs[k4 + 1][col] = v.y;
            Bs[k4 + 2][col] = v.z;
            Bs[k4 + 3][col] = v.w;
        }
        __syncthreads();
#pragma unroll 4
        for (int k = 0; k < 64; k++) {
            int sm = k & 28;  // read-side mask matches store-side
            float4 a0 = *(const float4*)(&As[k][ty * 8]);
            float4 a1 = *(const float4*)(&As[k][ty * 8 + 4]);
            float4 b0 = *(const float4*)(&Bs[k][(tx * 8) ^ sm]);
            float4 b1 = *(const float4*)(&Bs[k][(tx * 8 + 4) ^ sm]);
            float av[8] = {a0.x, a0.y, a0.z, a0.w, a1.x, a1.y, a1.z, a1.w};
            float bv[8] = {b0.x, b0.y, b0.z, b0.w, b1.x, b1.y, b1.z, b1.w};
#pragma unroll
            for (int i = 0; i < 8; i++)
#pragma unroll
                for (int j = 0; j < 8; j++)
                    acc[i][j] = fmaf(av[i], bv[j], acc[i][j]);
        }
        __syncthreads();
    }

    // epilogue: d = fl(A_row - 2*dot); argmin with lowest-index tie-break
#pragma unroll
    for (int i = 0; i < 8; i++) {
        float A = zn[row0 + ty * 8 + i];
        float vmin = FLT_MAX;
        float imin = 0.f;
#pragma unroll
        for (int j = 0; j < 8; j++) {
            float s = A - 2.f * acc[i][j];  // fma(-2,acc,A) == fl(A - 2*acc): 2*acc exact
            float cf = (float)(c0 + tx * 8 + j);
            if (s < vmin) { vmin = s; imin = cf; }  // strict < keeps lowest idx
        }
        // reduce across the 16 tx lanes sharing this row (same wave)
#pragma unroll
        for (int m = 1; m < 16; m <<= 1) {
            float v2 = __shfl_xor(vmin, m, 64);
            float i2 = __shfl_xor(imin, m, 64);
            if (v2 < vmin || (v2 == vmin && i2 < imin)) { vmin = v2; imin = i2; }
        }
        if (tx == 0) {
            // order-preserving float->uint map; pack (key<<32)|idx so atomicMin
            // yields global min with lowest-index tie-break (np.argmin semantics)
            unsigned int fb = __float_as_uint(vmin);
            fb ^= (fb & 0x80000000u) ? 0xFFFFFFFFu : 0x80000000u;
            unsigned long long pk =
                ((unsigned long long)fb << 32) | (unsigned long long)(unsigned int)(int)imin;
            atomicMin(&best[row0 + ty * 8 + i], pk);
        }
    }
}

// ---------------- kernel 3: min_idx as float ----------------
__global__ void k_widx(const unsigned long long* __restrict__ best,
                       float* __restrict__ oidx) {
    int n = blockIdx.x * 256 + threadIdx.x;
    oidx[n] = (float)(unsigned int)(best[n] & 0xFFFFFFFFull);
}

// ---------------- kernel 4: gather z_q + loss ----------------
// block = (b, c) pair; 256 threads x 4 hw elements, coalesced over hw
__global__ void k_gather(const float* __restrict__ z, const float* __restrict__ emb,
                         const unsigned long long* __restrict__ best,
                         float* __restrict__ zq, float* __restrict__ loss) {
    int b = blockIdx.x >> 8;
    int c = blockIdx.x & 255;
    int t = threadIdx.x;
    int hw = t << 2;
    const unsigned long long* bp = best + b * HW1 + hw;
    int i0 = (int)(unsigned int)(bp[0] & 0xFFFFFFFFull);
    int i1 = (int)(unsigned int)(bp[1] & 0xFFFFFFFFull);
    int i2 = (int)(unsigned int)(bp[2] & 0xFFFFFFFFull);
    int i3 = (int)(unsigned int)(bp[3] & 0xFFFFFFFFull);
    float e0 = emb[i0 * K_DIM + c];
    float e1 = emb[i1 * K_DIM + c];
    float e2 = emb[i2 * K_DIM + c];
    float e3 = emb[i3 * K_DIM + c];
    int off = b * (K_DIM * HW1) + c * HW1 + hw;
    float4 z4 = *(const float4*)(z + off);
    *(float4*)(zq + off) = make_float4(e0, e1, e2, e3);
    float d0 = e0 - z4.x, d1 = e1 - z4.y, d2 = e2 - z4.z, d3 = e3 - z4.w;
    float local = d0 * d0 + d1 * d1 + d2 * d2 + d3 * d3;
#pragma unroll
    for (int m = 32; m; m >>= 1) local += __shfl_xor(local, m, 64);
    if ((t & 63) == 0) atomicAdd(loss, local * (2.f / 4194304.f));
}

extern "C" void kernel_launch(void* const* d_in, const int* in_sizes, int n_in,
                              void* d_out, int out_size, void* d_ws, size_t ws_size,
                              hipStream_t stream) {
    const float* z = (const float*)d_in[0];
    const float* emb = (const float*)d_in[1];
    float* out = (float*)d_out;
    float* zq = out;
    float* loss = out + 4194304;
    float* oidx = out + 4194305;
    float* zn = (float*)d_ws;                                            // 64 KB
    unsigned long long* best = (unsigned long long*)((char*)d_ws + 65536);

    hipMemsetAsync(best, 0xFF, NROWS * sizeof(unsigned long long), stream);
    hipMemsetAsync(loss, 0, sizeof(float), stream);
    k_znorm<<<dim3(NROWS / 256), dim3(256), 0, stream>>>(z, zn);
    k_dist<<<dim3(NROWS / 128, NCODES / 128), dim3(256), 0, stream>>>(z, emb, zn, best);
    k_widx<<<dim3(NROWS / 256), dim3(256), 0, stream>>>(best, oidx);
    k_gather<<<dim3(16 * 256), dim3(256), 0, stream>>>(z, emb, best, zq, loss);
}

// Round 3
// 678.280 us; speedup vs baseline: 1.6792x; 1.6792x over previous
//
#include <hip/hip_runtime.h>
#include <hip/hip_fp16.h>
#include <float.h>

#define K_DIM 256
#define HW1 1024
#define NROWS 16384
#define NCODES 8192

typedef __attribute__((ext_vector_type(8))) short bf16x8;
typedef __attribute__((ext_vector_type(4))) float f32x4;

__device__ __forceinline__ ushort bf16rn(float x) {
    unsigned u = __float_as_uint(x);
    return (ushort)((u + 0x7FFFu + ((u >> 16) & 1u)) >> 16);
}

__device__ __forceinline__ void gl16(const void* g, void* l) {
    __builtin_amdgcn_global_load_lds((const __attribute__((address_space(1))) void*)g,
                                     (__attribute__((address_space(3))) void*)l, 16, 0, 0);
}

// ---- kernel 1: transpose z [b][k][hw] -> zf32 [n][k] (into zq out region) + bf16 copy ----
__global__ void k_cvt_z(const float* __restrict__ z, float* __restrict__ zf32,
                        ushort* __restrict__ z16) {
    __shared__ float ls[64][257];  // +1 pad: write-out reads ls[4c+kk][r] at 2-way (free)
    const int b = blockIdx.x, k0 = blockIdx.y * 64, hw0 = blockIdx.z * 256;
    const int tid = threadIdx.x;
    const float* src = z + (size_t)b * 262144 + (size_t)k0 * 1024 + hw0;
#pragma unroll
    for (int i = 0; i < 16; ++i) {
        int f = tid + i * 256;
        int kl = f >> 6, c4 = f & 63;
        float4 v = *(const float4*)(src + kl * 1024 + c4 * 4);
        ls[kl][c4 * 4 + 0] = v.x; ls[kl][c4 * 4 + 1] = v.y;
        ls[kl][c4 * 4 + 2] = v.z; ls[kl][c4 * 4 + 3] = v.w;
    }
    __syncthreads();
#pragma unroll
    for (int i = 0; i < 16; ++i) {
        int f = tid + i * 256;
        int r = f >> 4, ck = f & 15;
        float x0 = ls[ck * 4 + 0][r], x1 = ls[ck * 4 + 1][r];
        float x2 = ls[ck * 4 + 2][r], x3 = ls[ck * 4 + 3][r];
        int n = b * 1024 + hw0 + r;
        size_t off = (size_t)n * 256 + k0 + ck * 4;
        *(float4*)(zf32 + off) = make_float4(x0, x1, x2, x3);
        ushort4 h;
        h.x = bf16rn(x0); h.y = bf16rn(x1); h.z = bf16rn(x2); h.w = bf16rn(x3);
        *(ushort4*)(z16 + off) = h;
    }
}

// ---- kernel 2: emb fp32 -> bf16 ----
__global__ void k_cvt_e(const float* __restrict__ emb, ushort* __restrict__ e16) {
    int f = blockIdx.x * 256 + threadIdx.x;
    float4 v = *(const float4*)(emb + (size_t)f * 4);
    ushort4 h;
    h.x = bf16rn(v.x); h.y = bf16rn(v.y); h.z = bf16rn(v.z); h.w = bf16rn(v.w);
    *(ushort4*)(e16 + (size_t)f * 4) = h;
}

// ---- kernel 3: A[n] = ||z_row||^2, numpy pairwise order (exact, unchanged) ----
__global__ void k_znorm(const float* __restrict__ z, float* __restrict__ zn) {
    int n = blockIdx.x * 256 + threadIdx.x;
    int b = n >> 10;
    int hw = n & 1023;
    const float* p = z + b * (K_DIM * HW1) + hw;
    float half[2];
#pragma unroll
    for (int h = 0; h < 2; h++) {
        float r[8];
#pragma unroll
        for (int j = 0; j < 8; j++) {
            float v = p[(h * 128 + j) * HW1];
            float s = v * v;
            asm volatile("" : "+v"(s));
            r[j] = s;
        }
        for (int i = 8; i < 128; i += 8) {
#pragma unroll
            for (int j = 0; j < 8; j++) {
                float v = p[(h * 128 + i + j) * HW1];
                float s = v * v;
                asm volatile("" : "+v"(s));
                r[j] += s;
            }
        }
        half[h] = ((r[0] + r[1]) + (r[2] + r[3])) + ((r[4] + r[5]) + (r[6] + r[7]));
    }
    zn[n] = half[0] + half[1];
}

// ---- kernel 4: bf16 MFMA coarse pass: per-(row, 32-code group) max of z.e ----
// 128x128 tile, K=256 in 4 chunks of 64. LDS lane-linear rows of 128B with
// XOR swizzle applied on the GLOBAL address side so global_load_lds stays legal
// and frag ds_read_b128 is bank-balanced (8-cycle minimum, no hot bank).
__global__ __launch_bounds__(256, 2) void k_coarse(
    const ushort* __restrict__ z16, const ushort* __restrict__ e16,
    ushort* __restrict__ tbl) {
    __shared__ char smem[32768];
    char* As = smem;
    char* Bs = smem + 16384;
    const int tid = threadIdx.x;
    const int w = tid >> 6, lane = tid & 63;
    const int tx = lane & 15, q = lane >> 4;
    const int row0 = blockIdx.x * 128, c0 = blockIdx.y * 128;

    f32x4 acc[4][4];
#pragma unroll
    for (int mi = 0; mi < 4; ++mi)
#pragma unroll
        for (int ni = 0; ni < 4; ++ni) acc[mi][ni] = (f32x4){0.f, 0.f, 0.f, 0.f};

    for (int k0 = 0; k0 < K_DIM; k0 += 64) {
#pragma unroll
        for (int j = 0; j < 4; ++j) {
            int r = (w * 4 + j) * 8 + (lane >> 3);
            int c = (lane & 7) ^ (r & 7);  // inverse swizzle on global side
            gl16(z16 + (((size_t)(row0 + r)) << 8) + k0 + (c << 3),
                 As + (w * 4 + j) * 1024);
            gl16(e16 + (((size_t)(c0 + r)) << 8) + k0 + (c << 3),
                 Bs + (w * 4 + j) * 1024);
        }
        __syncthreads();
#pragma unroll
        for (int ks = 0; ks < 2; ++ks) {
            int cd = ks * 4;
            const int rAb = (w & 1) * 64, rBb = (w >> 1) * 64;
            bf16x8 af[4], bfv[4];
#pragma unroll
            for (int mi = 0; mi < 4; ++mi)
                af[mi] = *(const bf16x8*)(As + (rAb + mi * 16 + tx) * 128 +
                                          (((cd + q) ^ (tx & 7)) << 4));
#pragma unroll
            for (int ni = 0; ni < 4; ++ni)
                bfv[ni] = *(const bf16x8*)(Bs + (rBb + ni * 16 + tx) * 128 +
                                           (((cd + q) ^ (tx & 7)) << 4));
#pragma unroll
            for (int mi = 0; mi < 4; ++mi)
#pragma unroll
                for (int ni = 0; ni < 4; ++ni)
                    acc[mi][ni] = __builtin_amdgcn_mfma_f32_16x16x32_bf16(
                        af[mi], bfv[ni], acc[mi][ni], 0, 0, 0);
        }
        __syncthreads();
    }

    // epilogue: per row, max over each 32-col group; store f16 to tbl[group][n]
    const int rAb = (w & 1) * 64;
#pragma unroll
    for (int g = 0; g < 2; ++g) {
        int gidx = blockIdx.y * 4 + (w >> 1) * 2 + g;
#pragma unroll
        for (int mi = 0; mi < 4; ++mi) {
            float mv[4];
#pragma unroll
            for (int e = 0; e < 4; ++e)
                mv[e] = fmaxf(acc[mi][2 * g][e], acc[mi][2 * g + 1][e]);
#pragma unroll
            for (int msk = 1; msk < 16; msk <<= 1)
#pragma unroll
                for (int e = 0; e < 4; ++e)
                    mv[e] = fmaxf(mv[e], __shfl_xor(mv[e], msk, 64));
            if (tx == 0) {
                int n0 = row0 + rAb + mi * 16 + q * 4;  // reg e -> row n0+e
                ushort4 h4;
                h4.x = __half_as_ushort(__float2half(mv[0]));
                h4.y = __half_as_ushort(__float2half(mv[1]));
                h4.z = __half_as_ushort(__float2half(mv[2]));
                h4.w = __half_as_ushort(__float2half(mv[3]));
                *(ushort4*)(tbl + (size_t)gidx * NROWS + n0) = h4;
            }
        }
    }
}

// ---- kernel 5: exact fp32 rescore of flagged groups (bit-identical to round-2 math) ----
__global__ void k_rescore(const float* __restrict__ zf32, const float* __restrict__ emb,
                          const float* __restrict__ zn, const ushort* __restrict__ tbl,
                          int* __restrict__ bestidx, float* __restrict__ oidx) {
    const int n = blockIdx.x;
    const int t = threadIdx.x;  // 64 threads
    __shared__ float zs[256];
    *(float4*)(zs + t * 4) = *(const float4*)(zf32 + (size_t)n * 256 + t * 4);
    __syncthreads();
    const float A = zn[n];
    float gm[4];
#pragma unroll
    for (int i = 0; i < 4; ++i)
        gm[i] = __half2float(((const __half*)tbl)[(size_t)(i * 64 + t) * NROWS + n]);
    float gmax = fmaxf(fmaxf(gm[0], gm[1]), fmaxf(gm[2], gm[3]));
#pragma unroll
    for (int m = 1; m < 64; m <<= 1) gmax = fmaxf(gmax, __shfl_xor(gmax, m, 64));
    const float th = gmax - 1.0e-4f;  // provable capture margin (coarse err + grid + f16)

    float vmin = FLT_MAX;
    int imin = 0;
    for (int gq = 0; gq < 4; ++gq) {
        float gsrc = gm[gq];
        for (int g2 = 0; g2 < 64; ++g2) {
            float gv = __shfl(gsrc, g2, 64);
            if (gv < th) continue;  // wave-uniform branch
            int code = (gq * 64 + g2) * 32 + (t & 31);
            const float* e = emb + (size_t)code * 256;
            float acc = 0.f;
#pragma unroll 8
            for (int kk = 0; kk < 64; ++kk) {
                float4 e4 = *(const float4*)(e + kk * 4);
                acc = fmaf(zs[kk * 4 + 0], e4.x, acc);
                acc = fmaf(zs[kk * 4 + 1], e4.y, acc);
                acc = fmaf(zs[kk * 4 + 2], e4.z, acc);
                acc = fmaf(zs[kk * 4 + 3], e4.w, acc);
            }
            float d = A - 2.f * acc;  // same bits as round-2 passing kernel
            if (d < vmin) { vmin = d; imin = code; }
        }
    }
    unsigned fb = __float_as_uint(vmin);
    fb ^= (fb & 0x80000000u) ? 0xFFFFFFFFu : 0x80000000u;
    unsigned long long pk = ((unsigned long long)fb << 32) | (unsigned)imin;
#pragma unroll
    for (int m = 1; m < 64; m <<= 1) {
        unsigned long long o = __shfl_xor(pk, m, 64);
        if (o < pk) pk = o;
    }
    if (t == 0) {
        int bi = (int)(pk & 0xFFFFFFFFu);
        bestidx[n] = bi;
        oidx[n] = (float)bi;
    }
}

// ---- kernel 6: gather z_q + loss ----
__global__ void k_gather(const float* __restrict__ z, const float* __restrict__ emb,
                         const int* __restrict__ bestidx,
                         float* __restrict__ zq, float* __restrict__ loss) {
    int b = blockIdx.x >> 8;
    int c = blockIdx.x & 255;
    int t = threadIdx.x;
    int hw = t << 2;
    const int* bp = bestidx + b * HW1 + hw;
    int i0 = bp[0], i1 = bp[1], i2 = bp[2], i3 = bp[3];
    float e0 = emb[i0 * K_DIM + c];
    float e1 = emb[i1 * K_DIM + c];
    float e2 = emb[i2 * K_DIM + c];
    float e3 = emb[i3 * K_DIM + c];
    int off = b * (K_DIM * HW1) + c * HW1 + hw;
    float4 z4 = *(const float4*)(z + off);
    *(float4*)(zq + off) = make_float4(e0, e1, e2, e3);
    float d0 = e0 - z4.x, d1 = e1 - z4.y, d2 = e2 - z4.z, d3 = e3 - z4.w;
    float local = d0 * d0 + d1 * d1 + d2 * d2 + d3 * d3;
#pragma unroll
    for (int m = 32; m; m >>= 1) local += __shfl_xor(local, m, 64);
    if ((t & 63) == 0) atomicAdd(loss, local * (2.f / 4194304.f));
}

extern "C" void kernel_launch(void* const* d_in, const int* in_sizes, int n_in,
                              void* d_out, int out_size, void* d_ws, size_t ws_size,
                              hipStream_t stream) {
    const float* z = (const float*)d_in[0];
    const float* emb = (const float*)d_in[1];
    float* out = (float*)d_out;
    float* zq = out;
    float* loss = out + 4194304;
    float* oidx = out + 4194305;
    float* zf32 = out;  // zq region doubles as transposed-z scratch until k_gather

    ushort* z16 = (ushort*)d_ws;               // 8 MB
    ushort* e16 = z16 + 4194304;               // 4 MB
    ushort* tbl = e16 + 2097152;               // 8 MB (256 groups x 16384 rows, f16)
    float* zn = (float*)(tbl + 4194304);       // 64 KB
    int* bestidx = (int*)(zn + 16384);         // 64 KB

    hipMemsetAsync(loss, 0, sizeof(float), stream);
    k_cvt_z<<<dim3(16, 4, 4), dim3(256), 0, stream>>>(z, zf32, z16);
    k_cvt_e<<<dim3(2048), dim3(256), 0, stream>>>(emb, e16);
    k_znorm<<<dim3(NROWS / 256), dim3(256), 0, stream>>>(z, zn);
    k_coarse<<<dim3(NROWS / 128, NCODES / 128), dim3(256), 0, stream>>>(z16, e16, tbl);
    k_rescore<<<dim3(NROWS), dim3(64), 0, stream>>>(zf32, emb, zn, tbl, bestidx, oidx);
    k_gather<<<dim3(16 * 256), dim3(256), 0, stream>>>(z, emb, bestidx, zq, loss);
}

// Round 5
// 662.764 us; speedup vs baseline: 1.7185x; 1.0234x over previous
//
#include <hip/hip_runtime.h>
#include <hip/hip_fp16.h>
#include <float.h>

#define K_DIM 256
#define HW1 1024
#define NROWS 16384
#define NCODES 8192

typedef __attribute__((ext_vector_type(8))) short bf16x8;
typedef __attribute__((ext_vector_type(4))) float f32x4;

__device__ __forceinline__ ushort bf16rn(float x) {
    unsigned u = __float_as_uint(x);
    return (ushort)((u + 0x7FFFu + ((u >> 16) & 1u)) >> 16);
}

__device__ __forceinline__ void gl16(const void* g, void* l) {
    __builtin_amdgcn_global_load_lds((const __attribute__((address_space(1))) void*)g,
                                     (__attribute__((address_space(3))) void*)l, 16, 0, 0);
}

// ---- kernel 1: transpose z [b][k][hw] -> zf32 [n][k] (into zq out region) + bf16 copy ----
__global__ void k_cvt_z(const float* __restrict__ z, float* __restrict__ zf32,
                        ushort* __restrict__ z16) {
    __shared__ float ls[64][257];
    const int b = blockIdx.x, k0 = blockIdx.y * 64, hw0 = blockIdx.z * 256;
    const int tid = threadIdx.x;
    const float* src = z + (size_t)b * 262144 + (size_t)k0 * 1024 + hw0;
#pragma unroll
    for (int i = 0; i < 16; ++i) {
        int f = tid + i * 256;
        int kl = f >> 6, c4 = f & 63;
        float4 v = *(const float4*)(src + kl * 1024 + c4 * 4);
        ls[kl][c4 * 4 + 0] = v.x; ls[kl][c4 * 4 + 1] = v.y;
        ls[kl][c4 * 4 + 2] = v.z; ls[kl][c4 * 4 + 3] = v.w;
    }
    __syncthreads();
#pragma unroll
    for (int i = 0; i < 16; ++i) {
        int f = tid + i * 256;
        int r = f >> 4, ck = f & 15;
        float x0 = ls[ck * 4 + 0][r], x1 = ls[ck * 4 + 1][r];
        float x2 = ls[ck * 4 + 2][r], x3 = ls[ck * 4 + 3][r];
        int n = b * 1024 + hw0 + r;
        size_t off = (size_t)n * 256 + k0 + ck * 4;
        *(float4*)(zf32 + off) = make_float4(x0, x1, x2, x3);
        ushort4 h;
        h.x = bf16rn(x0); h.y = bf16rn(x1); h.z = bf16rn(x2); h.w = bf16rn(x3);
        *(ushort4*)(z16 + off) = h;
    }
}

// ---- kernel 2: emb fp32 -> bf16 ----
__global__ void k_cvt_e(const float* __restrict__ emb, ushort* __restrict__ e16) {
    int f = blockIdx.x * 256 + threadIdx.x;
    float4 v = *(const float4*)(emb + (size_t)f * 4);
    ushort4 h;
    h.x = bf16rn(v.x); h.y = bf16rn(v.y); h.z = bf16rn(v.z); h.w = bf16rn(v.w);
    *(ushort4*)(e16 + (size_t)f * 4) = h;
}

// ---- kernel 3: A[n] = ||z_row||^2, numpy pairwise order (exact, unchanged) ----
__global__ void k_znorm(const float* __restrict__ z, float* __restrict__ zn) {
    int n = blockIdx.x * 256 + threadIdx.x;
    int b = n >> 10;
    int hw = n & 1023;
    const float* p = z + b * (K_DIM * HW1) + hw;
    float half[2];
#pragma unroll
    for (int h = 0; h < 2; h++) {
        float r[8];
#pragma unroll
        for (int j = 0; j < 8; j++) {
            float v = p[(h * 128 + j) * HW1];
            float s = v * v;
            asm volatile("" : "+v"(s));
            r[j] = s;
        }
        for (int i = 8; i < 128; i += 8) {
#pragma unroll
            for (int j = 0; j < 8; j++) {
                float v = p[(h * 128 + i + j) * HW1];
                float s = v * v;
                asm volatile("" : "+v"(s));
                r[j] += s;
            }
        }
        half[h] = ((r[0] + r[1]) + (r[2] + r[3])) + ((r[4] + r[5]) + (r[6] + r[7]));
    }
    zn[n] = half[0] + half[1];
}

// ---- kernel 4: bf16 MFMA coarse pass: per-(row, 32-code group) max of z.e ----
// tbl layout [n][256 groups] f16 so rescore reads are contiguous.
__global__ __launch_bounds__(256, 2) void k_coarse(
    const ushort* __restrict__ z16, const ushort* __restrict__ e16,
    ushort* __restrict__ tbl) {
    __shared__ char smem[32768];
    char* As = smem;
    char* Bs = smem + 16384;
    const int tid = threadIdx.x;
    const int w = tid >> 6, lane = tid & 63;
    const int tx = lane & 15, q = lane >> 4;
    const int row0 = blockIdx.x * 128, c0 = blockIdx.y * 128;

    f32x4 acc[4][4];
#pragma unroll
    for (int mi = 0; mi < 4; ++mi)
#pragma unroll
        for (int ni = 0; ni < 4; ++ni) acc[mi][ni] = (f32x4){0.f, 0.f, 0.f, 0.f};

    for (int k0 = 0; k0 < K_DIM; k0 += 64) {
#pragma unroll
        for (int j = 0; j < 4; ++j) {
            int r = (w * 4 + j) * 8 + (lane >> 3);
            int c = (lane & 7) ^ (r & 7);  // inverse swizzle on global side
            gl16(z16 + (((size_t)(row0 + r)) << 8) + k0 + (c << 3),
                 As + (w * 4 + j) * 1024);
            gl16(e16 + (((size_t)(c0 + r)) << 8) + k0 + (c << 3),
                 Bs + (w * 4 + j) * 1024);
        }
        __syncthreads();
#pragma unroll
        for (int ks = 0; ks < 2; ++ks) {
            int cd = ks * 4;
            const int rAb = (w & 1) * 64, rBb = (w >> 1) * 64;
            bf16x8 af[4], bfv[4];
#pragma unroll
            for (int mi = 0; mi < 4; ++mi)
                af[mi] = *(const bf16x8*)(As + (rAb + mi * 16 + tx) * 128 +
                                          (((cd + q) ^ (tx & 7)) << 4));
#pragma unroll
            for (int ni = 0; ni < 4; ++ni)
                bfv[ni] = *(const bf16x8*)(Bs + (rBb + ni * 16 + tx) * 128 +
                                           (((cd + q) ^ (tx & 7)) << 4));
#pragma unroll
            for (int mi = 0; mi < 4; ++mi)
#pragma unroll
                for (int ni = 0; ni < 4; ++ni)
                    acc[mi][ni] = __builtin_amdgcn_mfma_f32_16x16x32_bf16(
                        af[mi], bfv[ni], acc[mi][ni], 0, 0, 0);
        }
        __syncthreads();
    }

    // epilogue: per row, max over each 32-col group; stage in LDS, then one
    // ushort4 per row -> tbl[n][blockIdx.y*4 .. +3]
    ushort* tb = (ushort*)smem;  // [128][4]
    const int rAb = (w & 1) * 64;
#pragma unroll
    for (int g = 0; g < 2; ++g) {
        int gcol = (w >> 1) * 2 + g;
#pragma unroll
        for (int mi = 0; mi < 4; ++mi) {
            float mv[4];
#pragma unroll
            for (int e = 0; e < 4; ++e)
                mv[e] = fmaxf(acc[mi][2 * g][e], acc[mi][2 * g + 1][e]);
#pragma unroll
            for (int msk = 1; msk < 16; msk <<= 1)
#pragma unroll
                for (int e = 0; e < 4; ++e)
                    mv[e] = fmaxf(mv[e], __shfl_xor(mv[e], msk, 64));
            if (tx == 0) {
                int rl = rAb + mi * 16 + q * 4;  // local row for reg e -> rl+e
#pragma unroll
                for (int e = 0; e < 4; ++e)
                    tb[(rl + e) * 4 + gcol] = __half_as_ushort(__float2half(mv[e]));
            }
        }
    }
    __syncthreads();
    if (tid < 128) {
        ushort4 v = *(ushort4*)(tb + tid * 4);
        *(ushort4*)(tbl + (size_t)(row0 + tid) * 256 + blockIdx.y * 4) = v;
    }
}

// ---- kernel 5: exact fp32 rescore of flagged groups (bit-identical math) ----
// FIX vs round 4: g2 OUTER / gq INNER so per-lane group visit order is
// strictly increasing (0,1,2,...). Per-lane strict-< then keeps the LOWEST
// code among exact fp32 ties (np.argmin semantics); round 4's inverted
// nesting visited 0,4,8,...,1,5,... and flipped tied rows.
__global__ void k_rescore(const float* __restrict__ zf32, const float* __restrict__ emb,
                          const float* __restrict__ zn, const ushort* __restrict__ tbl,
                          int* __restrict__ bestidx, float* __restrict__ oidx) {
    const int n = blockIdx.x;
    const int t = threadIdx.x;  // 64 threads
    __shared__ float zs[256];
    *(float4*)(zs + t * 4) = *(const float4*)(zf32 + (size_t)n * 256 + t * 4);
    __syncthreads();
    const float A = zn[n];
    const __half* hp = (const __half*)(tbl + (size_t)n * 256);
    float gm[4];
#pragma unroll
    for (int i = 0; i < 4; ++i) gm[i] = __half2float(hp[t * 4 + i]);  // group t*4+i
    float gmax = fmaxf(fmaxf(gm[0], gm[1]), fmaxf(gm[2], gm[3]));
#pragma unroll
    for (int m = 1; m < 64; m <<= 1) gmax = fmaxf(gmax, __shfl_xor(gmax, m, 64));
    const float th = gmax - 1.0e-4f;  // provable capture margin

    float vmin = FLT_MAX;
    int imin = 0;
    for (int g2 = 0; g2 < 64; ++g2) {
#pragma unroll
        for (int gq = 0; gq < 4; ++gq) {
            float gv = __shfl(gm[gq], g2, 64);
            if (gv < th) continue;  // wave-uniform branch
            int code = (g2 * 4 + gq) * 32 + (t & 31);  // group id = g2*4+gq
            const float* e = emb + (size_t)code * 256;
            float acc = 0.f;
#pragma unroll 8
            for (int kk = 0; kk < 64; ++kk) {
                float4 e4 = *(const float4*)(e + kk * 4);
                acc = fmaf(zs[kk * 4 + 0], e4.x, acc);
                acc = fmaf(zs[kk * 4 + 1], e4.y, acc);
                acc = fmaf(zs[kk * 4 + 2], e4.z, acc);
                acc = fmaf(zs[kk * 4 + 3], e4.w, acc);
            }
            float d = A - 2.f * acc;  // same bits as round-2 passing kernel
            if (d < vmin) { vmin = d; imin = code; }
        }
    }
    unsigned fb = __float_as_uint(vmin);
    fb ^= (fb & 0x80000000u) ? 0xFFFFFFFFu : 0x80000000u;
    unsigned long long pk = ((unsigned long long)fb << 32) | (unsigned)imin;
#pragma unroll
    for (int m = 1; m < 64; m <<= 1) {
        unsigned long long o = __shfl_xor(pk, m, 64);
        if (o < pk) pk = o;
    }
    if (t == 0) {
        int bi = (int)(pk & 0xFFFFFFFFu);
        bestidx[n] = bi;
        oidx[n] = (float)bi;
    }
}

// ---- kernel 6: transpose emb -> embT[c][code] (runs after rescore, reuses tbl) ----
__global__ void k_cvt_et(const float* __restrict__ emb, float* __restrict__ embT) {
    __shared__ float ls[64][129];  // [c_local][code_local(128)]
    const int c0 = blockIdx.x * 64, code0 = blockIdx.y * 128;
    const int t = threadIdx.x;
#pragma unroll
    for (int i = 0; i < 8; ++i) {
        int f = t + i * 256;                 // 128 codes x 16 float4
        int cl = f >> 4, c4 = f & 15;
        float4 v = *(const float4*)(emb + (size_t)(code0 + cl) * 256 + c0 + c4 * 4);
        ls[c4 * 4 + 0][cl] = v.x; ls[c4 * 4 + 1][cl] = v.y;
        ls[c4 * 4 + 2][cl] = v.z; ls[c4 * 4 + 3][cl] = v.w;
    }
    __syncthreads();
#pragma unroll
    for (int i = 0; i < 8; ++i) {
        int f = t + i * 256;                 // 64 c x 32 float4
        int cl = f >> 5, q4 = f & 31;
        float4 v = make_float4(ls[cl][q4 * 4 + 0], ls[cl][q4 * 4 + 1],
                               ls[cl][q4 * 4 + 2], ls[cl][q4 * 4 + 3]);
        *(float4*)(embT + (size_t)(c0 + cl) * NCODES + code0 + q4 * 4) = v;
    }
}

// ---- kernel 7: gather z_q + loss via LDS-cached embT column ----
__global__ void k_gather(const float* __restrict__ z, const float* __restrict__ embT,
                         const int* __restrict__ bestidx,
                         float* __restrict__ zq, float* __restrict__ loss) {
    __shared__ float ec[NCODES];  // 32 KB: embT[c][*]
    int b = blockIdx.x >> 8;
    int c = blockIdx.x & 255;
    int t = threadIdx.x;
    const float* src = embT + (size_t)c * NCODES;
#pragma unroll
    for (int i = 0; i < 8; ++i)
        *(float4*)(ec + t * 4 + i * 1024) = *(const float4*)(src + t * 4 + i * 1024);
    __syncthreads();
    int hw = t << 2;
    const int* bp = bestidx + b * HW1 + hw;
    float e0 = ec[bp[0]], e1 = ec[bp[1]], e2 = ec[bp[2]], e3 = ec[bp[3]];
    int off = b * (K_DIM * HW1) + c * HW1 + hw;
    float4 z4 = *(const float4*)(z + off);
    *(float4*)(zq + off) = make_float4(e0, e1, e2, e3);
    float d0 = e0 - z4.x, d1 = e1 - z4.y, d2 = e2 - z4.z, d3 = e3 - z4.w;
    float local = d0 * d0 + d1 * d1 + d2 * d2 + d3 * d3;
#pragma unroll
    for (int m = 32; m; m >>= 1) local += __shfl_xor(local, m, 64);
    if ((t & 63) == 0) atomicAdd(loss, local * (2.f / 4194304.f));
}

extern "C" void kernel_launch(void* const* d_in, const int* in_sizes, int n_in,
                              void* d_out, int out_size, void* d_ws, size_t ws_size,
                              hipStream_t stream) {
    const float* z = (const float*)d_in[0];
    const float* emb = (const float*)d_in[1];
    float* out = (float*)d_out;
    float* zq = out;
    float* loss = out + 4194304;
    float* oidx = out + 4194305;
    float* zf32 = out;  // zq region doubles as transposed-z scratch until k_gather

    ushort* z16 = (ushort*)d_ws;               // 8 MB
    ushort* e16 = z16 + 4194304;               // 4 MB
    ushort* tbl = e16 + 2097152;               // 8 MB [n][256] f16; reused as embT after rescore
    float* zn = (float*)(tbl + 4194304);       // 64 KB
    int* bestidx = (int*)(zn + 16384);         // 64 KB
    float* embT = (float*)tbl;                 // 8 MB fp32, alias (post-rescore)

    hipMemsetAsync(loss, 0, sizeof(float), stream);
    k_cvt_z<<<dim3(16, 4, 4), dim3(256), 0, stream>>>(z, zf32, z16);
    k_cvt_e<<<dim3(2048), dim3(256), 0, stream>>>(emb, e16);
    k_znorm<<<dim3(NROWS / 256), dim3(256), 0, stream>>>(z, zn);
    k_coarse<<<dim3(NROWS / 128, NCODES / 128), dim3(256), 0, stream>>>(z16, e16, tbl);
    k_rescore<<<dim3(NROWS), dim3(64), 0, stream>>>(zf32, emb, zn, tbl, bestidx, oidx);
    k_cvt_et<<<dim3(4, 64), dim3(256), 0, stream>>>(emb, embT);
    k_gather<<<dim3(16 * 256), dim3(256), 0, stream>>>(z, embT, bestidx, zq, loss);
}

// Round 6
// 564.970 us; speedup vs baseline: 2.0159x; 1.1731x over previous
//
#include <hip/hip_runtime.h>
#include <hip/hip_fp16.h>
#include <float.h>

#define K_DIM 256
#define HW1 1024
#define NROWS 16384
#define NCODES 8192

typedef __attribute__((ext_vector_type(8))) short bf16x8;
typedef __attribute__((ext_vector_type(4))) float f32x4;

__device__ __forceinline__ ushort bf16rn(float x) {
    unsigned u = __float_as_uint(x);
    return (ushort)((u + 0x7FFFu + ((u >> 16) & 1u)) >> 16);
}

__device__ __forceinline__ void gl16(const void* g, void* l) {
    __builtin_amdgcn_global_load_lds((const __attribute__((address_space(1))) void*)g,
                                     (__attribute__((address_space(3))) void*)l, 16, 0, 0);
}

// ---- kernel 1: transpose z [b][k][hw] -> zf32 [n][k] (into zq out region) + bf16 copy ----
__global__ void k_cvt_z(const float* __restrict__ z, float* __restrict__ zf32,
                        ushort* __restrict__ z16) {
    __shared__ float ls[64][257];
    const int b = blockIdx.x, k0 = blockIdx.y * 64, hw0 = blockIdx.z * 256;
    const int tid = threadIdx.x;
    const float* src = z + (size_t)b * 262144 + (size_t)k0 * 1024 + hw0;
#pragma unroll
    for (int i = 0; i < 16; ++i) {
        int f = tid + i * 256;
        int kl = f >> 6, c4 = f & 63;
        float4 v = *(const float4*)(src + kl * 1024 + c4 * 4);
        ls[kl][c4 * 4 + 0] = v.x; ls[kl][c4 * 4 + 1] = v.y;
        ls[kl][c4 * 4 + 2] = v.z; ls[kl][c4 * 4 + 3] = v.w;
    }
    __syncthreads();
#pragma unroll
    for (int i = 0; i < 16; ++i) {
        int f = tid + i * 256;
        int r = f >> 4, ck = f & 15;
        float x0 = ls[ck * 4 + 0][r], x1 = ls[ck * 4 + 1][r];
        float x2 = ls[ck * 4 + 2][r], x3 = ls[ck * 4 + 3][r];
        int n = b * 1024 + hw0 + r;
        size_t off = (size_t)n * 256 + k0 + ck * 4;
        *(float4*)(zf32 + off) = make_float4(x0, x1, x2, x3);
        ushort4 h;
        h.x = bf16rn(x0); h.y = bf16rn(x1); h.z = bf16rn(x2); h.w = bf16rn(x3);
        *(ushort4*)(z16 + off) = h;
    }
}

// ---- kernel 2: emb fp32 -> bf16 ----
__global__ void k_cvt_e(const float* __restrict__ emb, ushort* __restrict__ e16) {
    int f = blockIdx.x * 256 + threadIdx.x;
    float4 v = *(const float4*)(emb + (size_t)f * 4);
    ushort4 h;
    h.x = bf16rn(v.x); h.y = bf16rn(v.y); h.z = bf16rn(v.z); h.w = bf16rn(v.w);
    *(ushort4*)(e16 + (size_t)f * 4) = h;
}

// ---- kernel 3: A[n] = ||z_row||^2, numpy pairwise order (exact, unchanged) ----
__global__ void k_znorm(const float* __restrict__ z, float* __restrict__ zn) {
    int n = blockIdx.x * 256 + threadIdx.x;
    int b = n >> 10;
    int hw = n & 1023;
    const float* p = z + b * (K_DIM * HW1) + hw;
    float half[2];
#pragma unroll
    for (int h = 0; h < 2; h++) {
        float r[8];
#pragma unroll
        for (int j = 0; j < 8; j++) {
            float v = p[(h * 128 + j) * HW1];
            float s = v * v;
            asm volatile("" : "+v"(s));
            r[j] = s;
        }
        for (int i = 8; i < 128; i += 8) {
#pragma unroll
            for (int j = 0; j < 8; j++) {
                float v = p[(h * 128 + i + j) * HW1];
                float s = v * v;
                asm volatile("" : "+v"(s));
                r[j] += s;
            }
        }
        half[h] = ((r[0] + r[1]) + (r[2] + r[3])) + ((r[4] + r[5]) + (r[6] + r[7]));
    }
    zn[n] = half[0] + half[1];
}

// ---- kernel 4: bf16 MFMA coarse pass: per-(row, 32-code group) max of z.e ----
__global__ __launch_bounds__(256, 2) void k_coarse(
    const ushort* __restrict__ z16, const ushort* __restrict__ e16,
    ushort* __restrict__ tbl) {
    __shared__ char smem[32768];
    char* As = smem;
    char* Bs = smem + 16384;
    const int tid = threadIdx.x;
    const int w = tid >> 6, lane = tid & 63;
    const int tx = lane & 15, q = lane >> 4;
    const int row0 = blockIdx.x * 128, c0 = blockIdx.y * 128;

    f32x4 acc[4][4];
#pragma unroll
    for (int mi = 0; mi < 4; ++mi)
#pragma unroll
        for (int ni = 0; ni < 4; ++ni) acc[mi][ni] = (f32x4){0.f, 0.f, 0.f, 0.f};

    for (int k0 = 0; k0 < K_DIM; k0 += 64) {
#pragma unroll
        for (int j = 0; j < 4; ++j) {
            int r = (w * 4 + j) * 8 + (lane >> 3);
            int c = (lane & 7) ^ (r & 7);  // inverse swizzle on global side
            gl16(z16 + (((size_t)(row0 + r)) << 8) + k0 + (c << 3),
                 As + (w * 4 + j) * 1024);
            gl16(e16 + (((size_t)(c0 + r)) << 8) + k0 + (c << 3),
                 Bs + (w * 4 + j) * 1024);
        }
        __syncthreads();
#pragma unroll
        for (int ks = 0; ks < 2; ++ks) {
            int cd = ks * 4;
            const int rAb = (w & 1) * 64, rBb = (w >> 1) * 64;
            bf16x8 af[4], bfv[4];
#pragma unroll
            for (int mi = 0; mi < 4; ++mi)
                af[mi] = *(const bf16x8*)(As + (rAb + mi * 16 + tx) * 128 +
                                          (((cd + q) ^ (tx & 7)) << 4));
#pragma unroll
            for (int ni = 0; ni < 4; ++ni)
                bfv[ni] = *(const bf16x8*)(Bs + (rBb + ni * 16 + tx) * 128 +
                                           (((cd + q) ^ (tx & 7)) << 4));
#pragma unroll
            for (int mi = 0; mi < 4; ++mi)
#pragma unroll
                for (int ni = 0; ni < 4; ++ni)
                    acc[mi][ni] = __builtin_amdgcn_mfma_f32_16x16x32_bf16(
                        af[mi], bfv[ni], acc[mi][ni], 0, 0, 0);
        }
        __syncthreads();
    }

    ushort* tb = (ushort*)smem;  // [128][4]
    const int rAb = (w & 1) * 64;
#pragma unroll
    for (int g = 0; g < 2; ++g) {
        int gcol = (w >> 1) * 2 + g;
#pragma unroll
        for (int mi = 0; mi < 4; ++mi) {
            float mv[4];
#pragma unroll
            for (int e = 0; e < 4; ++e)
                mv[e] = fmaxf(acc[mi][2 * g][e], acc[mi][2 * g + 1][e]);
#pragma unroll
            for (int msk = 1; msk < 16; msk <<= 1)
#pragma unroll
                for (int e = 0; e < 4; ++e)
                    mv[e] = fmaxf(mv[e], __shfl_xor(mv[e], msk, 64));
            if (tx == 0) {
                int rl = rAb + mi * 16 + q * 4;
#pragma unroll
                for (int e = 0; e < 4; ++e)
                    tb[(rl + e) * 4 + gcol] = __half_as_ushort(__float2half(mv[e]));
            }
        }
    }
    __syncthreads();
    if (tid < 128) {
        ushort4 v = *(ushort4*)(tb + tid * 4);
        *(ushort4*)(tbl + (size_t)(row0 + tid) * 256 + blockIdx.y * 4) = v;
    }
}

// ---- kernel 5a: flag pass — bucket rows by candidate group ----
// Bucket capacity 16384/group is the exact worst case (can't overflow).
__global__ void k_flag(const ushort* __restrict__ tbl, ushort* __restrict__ bucket,
                       unsigned* __restrict__ gcnt) {
    const int wid = threadIdx.x >> 6, lane = threadIdx.x & 63;
    const int n = blockIdx.x * 4 + wid;
    ushort4 raw = *(const ushort4*)(tbl + (size_t)n * 256 + lane * 4);
    float gm[4];
    gm[0] = __half2float(__ushort_as_half(raw.x));
    gm[1] = __half2float(__ushort_as_half(raw.y));
    gm[2] = __half2float(__ushort_as_half(raw.z));
    gm[3] = __half2float(__ushort_as_half(raw.w));
    float gmax = fmaxf(fmaxf(gm[0], gm[1]), fmaxf(gm[2], gm[3]));
#pragma unroll
    for (int m = 1; m < 64; m <<= 1) gmax = fmaxf(gmax, __shfl_xor(gmax, m, 64));
    const float th = gmax - 1.0e-4f;  // same capture margin as rounds 3/5
#pragma unroll
    for (int i = 0; i < 4; ++i) {
        if (gm[i] >= th) {
            int g = lane * 4 + i;
            unsigned pos = atomicAdd(&gcnt[g], 1u);
            bucket[(size_t)g * NROWS + pos] = (ushort)n;
        }
    }
}

// ---- kernel 5b: exact rescore, one block per group (emb group read ONCE) ----
// Bit-identical fp32 math: serial fmaf k=0..255, d = A - 2*acc. Global
// lowest-index tie-break via u64 atomicMin (order-independent).
__global__ __launch_bounds__(256) void k_rescore2(
    const float* __restrict__ zf32, const float* __restrict__ emb,
    const float* __restrict__ zn, const ushort* __restrict__ bucket,
    const unsigned* __restrict__ gcnt, unsigned long long* __restrict__ best) {
    __shared__ float eg[32 * 257];  // stride 257: lane-per-code reads conflict-free
    __shared__ float zs[8][256];
    __shared__ ushort rid[8];
    __shared__ float arow[8];
    const int g = blockIdx.x;
    const int t = threadIdx.x;
#pragma unroll
    for (int i = 0; i < 8; ++i) {
        int f = t + i * 256;  // 32 codes x 64 float4
        int c = f >> 6, k4 = f & 63;
        float4 v = *(const float4*)(emb + (size_t)(g * 32 + c) * 256 + k4 * 4);
        float* dst = eg + c * 257 + k4 * 4;
        dst[0] = v.x; dst[1] = v.y; dst[2] = v.z; dst[3] = v.w;
    }
    const int cnt = (int)gcnt[g];
    for (int base = 0; base < cnt; base += 8) {
        __syncthreads();
        if (t < 8) {
            int i = base + t;
            if (i < cnt) {
                ushort r = bucket[(size_t)g * NROWS + i];
                rid[t] = r;
                arow[t] = zn[r];
            } else {
                rid[t] = 0xFFFF;
            }
        }
        __syncthreads();
#pragma unroll
        for (int i = 0; i < 2; ++i) {  // 8 rows x 64 float4 = 512; 256 thr x 2
            int f = t + i * 256;
            int s = f >> 6, k4 = f & 63;
            if (rid[s] != 0xFFFF)
                *(float4*)(&zs[s][k4 * 4]) =
                    *(const float4*)(zf32 + (size_t)rid[s] * 256 + k4 * 4);
        }
        __syncthreads();
        const int lane = t & 63, w = t >> 6;
        const int slot = w * 2 + (lane >> 5);
        const int code = lane & 31;
        if (rid[slot] != 0xFFFF) {
            const float* zr = zs[slot];
            const float* er = eg + code * 257;
            float acc = 0.f;
#pragma unroll 8
            for (int k = 0; k < 256; ++k) acc = fmaf(zr[k], er[k], acc);
            float d = arow[slot] - 2.f * acc;  // same bits as round-2 kernel
            unsigned fb = __float_as_uint(d);
            fb ^= (fb & 0x80000000u) ? 0xFFFFFFFFu : 0x80000000u;
            unsigned long long pk =
                ((unsigned long long)fb << 32) | (unsigned)(g * 32 + code);
#pragma unroll
            for (int m = 1; m < 32; m <<= 1) {
                unsigned long long o = __shfl_xor(pk, m, 64);
                if (o < pk) pk = o;
            }
            if ((lane & 31) == 0) atomicMin(&best[rid[slot]], pk);
        }
    }
}

// ---- kernel 5c: unpack best -> bestidx + oidx ----
__global__ void k_widx(const unsigned long long* __restrict__ best,
                       int* __restrict__ bestidx, float* __restrict__ oidx) {
    int n = blockIdx.x * 256 + threadIdx.x;
    int bi = (int)(unsigned)(best[n] & 0xFFFFFFFFull);
    bestidx[n] = bi;
    oidx[n] = (float)bi;
}

// ---- kernel 6: transpose emb -> embT[c][code] (reuses tbl region) ----
__global__ void k_cvt_et(const float* __restrict__ emb, float* __restrict__ embT) {
    __shared__ float ls[64][129];
    const int c0 = blockIdx.x * 64, code0 = blockIdx.y * 128;
    const int t = threadIdx.x;
#pragma unroll
    for (int i = 0; i < 8; ++i) {
        int f = t + i * 256;
        int cl = f >> 4, c4 = f & 15;
        float4 v = *(const float4*)(emb + (size_t)(code0 + cl) * 256 + c0 + c4 * 4);
        ls[c4 * 4 + 0][cl] = v.x; ls[c4 * 4 + 1][cl] = v.y;
        ls[c4 * 4 + 2][cl] = v.z; ls[c4 * 4 + 3][cl] = v.w;
    }
    __syncthreads();
#pragma unroll
    for (int i = 0; i < 8; ++i) {
        int f = t + i * 256;
        int cl = f >> 5, q4 = f & 31;
        float4 v = make_float4(ls[cl][q4 * 4 + 0], ls[cl][q4 * 4 + 1],
                               ls[cl][q4 * 4 + 2], ls[cl][q4 * 4 + 3]);
        *(float4*)(embT + (size_t)(c0 + cl) * NCODES + code0 + q4 * 4) = v;
    }
}

// ---- kernel 7: gather z_q + loss via LDS-cached embT column ----
__global__ void k_gather(const float* __restrict__ z, const float* __restrict__ embT,
                         const int* __restrict__ bestidx,
                         float* __restrict__ zq, float* __restrict__ loss) {
    __shared__ float ec[NCODES];
    int b = blockIdx.x >> 8;
    int c = blockIdx.x & 255;
    int t = threadIdx.x;
    const float* src = embT + (size_t)c * NCODES;
#pragma unroll
    for (int i = 0; i < 8; ++i)
        *(float4*)(ec + t * 4 + i * 1024) = *(const float4*)(src + t * 4 + i * 1024);
    __syncthreads();
    int hw = t << 2;
    const int* bp = bestidx + b * HW1 + hw;
    float e0 = ec[bp[0]], e1 = ec[bp[1]], e2 = ec[bp[2]], e3 = ec[bp[3]];
    int off = b * (K_DIM * HW1) + c * HW1 + hw;
    float4 z4 = *(const float4*)(z + off);
    *(float4*)(zq + off) = make_float4(e0, e1, e2, e3);
    float d0 = e0 - z4.x, d1 = e1 - z4.y, d2 = e2 - z4.z, d3 = e3 - z4.w;
    float local = d0 * d0 + d1 * d1 + d2 * d2 + d3 * d3;
#pragma unroll
    for (int m = 32; m; m >>= 1) local += __shfl_xor(local, m, 64);
    if ((t & 63) == 0) atomicAdd(loss, local * (2.f / 4194304.f));
}

extern "C" void kernel_launch(void* const* d_in, const int* in_sizes, int n_in,
                              void* d_out, int out_size, void* d_ws, size_t ws_size,
                              hipStream_t stream) {
    const float* z = (const float*)d_in[0];
    const float* emb = (const float*)d_in[1];
    float* out = (float*)d_out;
    float* zq = out;
    float* loss = out + 4194304;
    float* oidx = out + 4194305;
    float* zf32 = out;  // zq region doubles as transposed-z scratch until k_gather

    ushort* z16 = (ushort*)d_ws;               // 8 MB; dead after k_coarse
    ushort* e16 = z16 + 4194304;               // 4 MB
    ushort* tbl = e16 + 2097152;               // 8 MB [n][256] f16; embT alias later
    float* zn = (float*)(tbl + 4194304);       // 64 KB
    int* bestidx = (int*)(zn + 16384);         // 64 KB
    unsigned long long* best = (unsigned long long*)(bestidx + 16384);  // 128 KB
    unsigned* gcnt = (unsigned*)(best + 16384);                          // 1 KB
    ushort* bucket = z16;                      // alias dead z16 (exactly 8 MB)
    float* embT = (float*)tbl;                 // alias (post-rescore)

    hipMemsetAsync(loss, 0, sizeof(float), stream);
    hipMemsetAsync(gcnt, 0, 256 * sizeof(unsigned), stream);
    hipMemsetAsync(best, 0xFF, NROWS * sizeof(unsigned long long), stream);
    k_cvt_z<<<dim3(16, 4, 4), dim3(256), 0, stream>>>(z, zf32, z16);
    k_cvt_e<<<dim3(2048), dim3(256), 0, stream>>>(emb, e16);
    k_znorm<<<dim3(NROWS / 256), dim3(256), 0, stream>>>(z, zn);
    k_coarse<<<dim3(NROWS / 128, NCODES / 128), dim3(256), 0, stream>>>(z16, e16, tbl);
    k_flag<<<dim3(NROWS / 4), dim3(256), 0, stream>>>(tbl, bucket, gcnt);
    k_rescore2<<<dim3(256), dim3(256), 0, stream>>>(zf32, emb, zn, bucket, gcnt, best);
    k_widx<<<dim3(NROWS / 256), dim3(256), 0, stream>>>(best, bestidx, oidx);
    k_cvt_et<<<dim3(4, 64), dim3(256), 0, stream>>>(emb, embT);
    k_gather<<<dim3(16 * 256), dim3(256), 0, stream>>>(z, embT, bestidx, zq, loss);
}

// Round 7
// 359.858 us; speedup vs baseline: 3.1650x; 1.5700x over previous
//
#include <hip/hip_runtime.h>
#include <hip/hip_fp16.h>
#include <float.h>

#define K_DIM 256
#define HW1 1024
#define NROWS 16384
#define NCODES 8192

typedef __attribute__((ext_vector_type(8))) short bf16x8;
typedef __attribute__((ext_vector_type(4))) float f32x4;

__device__ __forceinline__ ushort bf16rn(float x) {
    unsigned u = __float_as_uint(x);
    return (ushort)((u + 0x7FFFu + ((u >> 16) & 1u)) >> 16);
}

__device__ __forceinline__ void gl16(const void* g, void* l) {
    __builtin_amdgcn_global_load_lds((const __attribute__((address_space(1))) void*)g,
                                     (__attribute__((address_space(3))) void*)l, 16, 0, 0);
}

// ---- kernel 1: transpose z [b][k][hw] -> zf32 [n][k] (into zq out region) + bf16 copy ----
__global__ void k_cvt_z(const float* __restrict__ z, float* __restrict__ zf32,
                        ushort* __restrict__ z16) {
    __shared__ float ls[64][257];
    const int b = blockIdx.x, k0 = blockIdx.y * 64, hw0 = blockIdx.z * 256;
    const int tid = threadIdx.x;
    const float* src = z + (size_t)b * 262144 + (size_t)k0 * 1024 + hw0;
#pragma unroll
    for (int i = 0; i < 16; ++i) {
        int f = tid + i * 256;
        int kl = f >> 6, c4 = f & 63;
        float4 v = *(const float4*)(src + kl * 1024 + c4 * 4);
        ls[kl][c4 * 4 + 0] = v.x; ls[kl][c4 * 4 + 1] = v.y;
        ls[kl][c4 * 4 + 2] = v.z; ls[kl][c4 * 4 + 3] = v.w;
    }
    __syncthreads();
#pragma unroll
    for (int i = 0; i < 16; ++i) {
        int f = tid + i * 256;
        int r = f >> 4, ck = f & 15;
        float x0 = ls[ck * 4 + 0][r], x1 = ls[ck * 4 + 1][r];
        float x2 = ls[ck * 4 + 2][r], x3 = ls[ck * 4 + 3][r];
        int n = b * 1024 + hw0 + r;
        size_t off = (size_t)n * 256 + k0 + ck * 4;
        *(float4*)(zf32 + off) = make_float4(x0, x1, x2, x3);
        ushort4 h;
        h.x = bf16rn(x0); h.y = bf16rn(x1); h.z = bf16rn(x2); h.w = bf16rn(x3);
        *(ushort4*)(z16 + off) = h;
    }
}

// ---- kernel 2: emb fp32 -> bf16 ----
__global__ void k_cvt_e(const float* __restrict__ emb, ushort* __restrict__ e16) {
    int f = blockIdx.x * 256 + threadIdx.x;
    float4 v = *(const float4*)(emb + (size_t)f * 4);
    ushort4 h;
    h.x = bf16rn(v.x); h.y = bf16rn(v.y); h.z = bf16rn(v.z); h.w = bf16rn(v.w);
    *(ushort4*)(e16 + (size_t)f * 4) = h;
}

// ---- kernel 3: A[n] = ||z_row||^2, numpy pairwise order (exact, unchanged) ----
__global__ void k_znorm(const float* __restrict__ z, float* __restrict__ zn) {
    int n = blockIdx.x * 256 + threadIdx.x;
    int b = n >> 10;
    int hw = n & 1023;
    const float* p = z + b * (K_DIM * HW1) + hw;
    float half[2];
#pragma unroll
    for (int h = 0; h < 2; h++) {
        float r[8];
#pragma unroll
        for (int j = 0; j < 8; j++) {
            float v = p[(h * 128 + j) * HW1];
            float s = v * v;
            asm volatile("" : "+v"(s));
            r[j] = s;
        }
        for (int i = 8; i < 128; i += 8) {
#pragma unroll
            for (int j = 0; j < 8; j++) {
                float v = p[(h * 128 + i + j) * HW1];
                float s = v * v;
                asm volatile("" : "+v"(s));
                r[j] += s;
            }
        }
        half[h] = ((r[0] + r[1]) + (r[2] + r[3])) + ((r[4] + r[5]) + (r[6] + r[7]));
    }
    zn[n] = half[0] + half[1];
}

// ---- kernel 4: bf16 MFMA coarse pass: per-(row, 32-code group) max of z.e ----
__global__ __launch_bounds__(256, 2) void k_coarse(
    const ushort* __restrict__ z16, const ushort* __restrict__ e16,
    ushort* __restrict__ tbl) {
    __shared__ char smem[32768];
    char* As = smem;
    char* Bs = smem + 16384;
    const int tid = threadIdx.x;
    const int w = tid >> 6, lane = tid & 63;
    const int tx = lane & 15, q = lane >> 4;
    const int row0 = blockIdx.x * 128, c0 = blockIdx.y * 128;

    f32x4 acc[4][4];
#pragma unroll
    for (int mi = 0; mi < 4; ++mi)
#pragma unroll
        for (int ni = 0; ni < 4; ++ni) acc[mi][ni] = (f32x4){0.f, 0.f, 0.f, 0.f};

    for (int k0 = 0; k0 < K_DIM; k0 += 64) {
#pragma unroll
        for (int j = 0; j < 4; ++j) {
            int r = (w * 4 + j) * 8 + (lane >> 3);
            int c = (lane & 7) ^ (r & 7);  // inverse swizzle on global side
            gl16(z16 + (((size_t)(row0 + r)) << 8) + k0 + (c << 3),
                 As + (w * 4 + j) * 1024);
            gl16(e16 + (((size_t)(c0 + r)) << 8) + k0 + (c << 3),
                 Bs + (w * 4 + j) * 1024);
        }
        __syncthreads();
#pragma unroll
        for (int ks = 0; ks < 2; ++ks) {
            int cd = ks * 4;
            const int rAb = (w & 1) * 64, rBb = (w >> 1) * 64;
            bf16x8 af[4], bfv[4];
#pragma unroll
            for (int mi = 0; mi < 4; ++mi)
                af[mi] = *(const bf16x8*)(As + (rAb + mi * 16 + tx) * 128 +
                                          (((cd + q) ^ (tx & 7)) << 4));
#pragma unroll
            for (int ni = 0; ni < 4; ++ni)
                bfv[ni] = *(const bf16x8*)(Bs + (rBb + ni * 16 + tx) * 128 +
                                           (((cd + q) ^ (tx & 7)) << 4));
#pragma unroll
            for (int mi = 0; mi < 4; ++mi)
#pragma unroll
                for (int ni = 0; ni < 4; ++ni)
                    acc[mi][ni] = __builtin_amdgcn_mfma_f32_16x16x32_bf16(
                        af[mi], bfv[ni], acc[mi][ni], 0, 0, 0);
        }
        __syncthreads();
    }

    ushort* tb = (ushort*)smem;  // [128][4]
    const int rAb = (w & 1) * 64;
#pragma unroll
    for (int g = 0; g < 2; ++g) {
        int gcol = (w >> 1) * 2 + g;
#pragma unroll
        for (int mi = 0; mi < 4; ++mi) {
            float mv[4];
#pragma unroll
            for (int e = 0; e < 4; ++e)
                mv[e] = fmaxf(acc[mi][2 * g][e], acc[mi][2 * g + 1][e]);
#pragma unroll
            for (int msk = 1; msk < 16; msk <<= 1)
#pragma unroll
                for (int e = 0; e < 4; ++e)
                    mv[e] = fmaxf(mv[e], __shfl_xor(mv[e], msk, 64));
            if (tx == 0) {
                int rl = rAb + mi * 16 + q * 4;
#pragma unroll
                for (int e = 0; e < 4; ++e)
                    tb[(rl + e) * 4 + gcol] = __half_as_ushort(__float2half(mv[e]));
            }
        }
    }
    __syncthreads();
    if (tid < 128) {
        ushort4 v = *(ushort4*)(tb + tid * 4);
        *(ushort4*)(tbl + (size_t)(row0 + tid) * 256 + blockIdx.y * 4) = v;
    }
}

// ---- kernel 5a: flag pass — bucket rows by candidate group ----
__global__ void k_flag(const ushort* __restrict__ tbl, ushort* __restrict__ bucket,
                       unsigned* __restrict__ gcnt) {
    const int wid = threadIdx.x >> 6, lane = threadIdx.x & 63;
    const int n = blockIdx.x * 4 + wid;
    ushort4 raw = *(const ushort4*)(tbl + (size_t)n * 256 + lane * 4);
    float gm[4];
    gm[0] = __half2float(__ushort_as_half(raw.x));
    gm[1] = __half2float(__ushort_as_half(raw.y));
    gm[2] = __half2float(__ushort_as_half(raw.z));
    gm[3] = __half2float(__ushort_as_half(raw.w));
    float gmax = fmaxf(fmaxf(gm[0], gm[1]), fmaxf(gm[2], gm[3]));
#pragma unroll
    for (int m = 1; m < 64; m <<= 1) gmax = fmaxf(gmax, __shfl_xor(gmax, m, 64));
    const float th = gmax - 1.0e-4f;  // same capture margin as rounds 3/5
#pragma unroll
    for (int i = 0; i < 4; ++i) {
        if (gm[i] >= th) {
            int g = lane * 4 + i;
            unsigned pos = atomicAdd(&gcnt[g], 1u);
            bucket[(size_t)g * NROWS + pos] = (ushort)n;
        }
    }
}

// ---- kernel 5b: exact rescore, one block per group (emb group read ONCE) ----
__global__ __launch_bounds__(256) void k_rescore2(
    const float* __restrict__ zf32, const float* __restrict__ emb,
    const float* __restrict__ zn, const ushort* __restrict__ bucket,
    const unsigned* __restrict__ gcnt, unsigned long long* __restrict__ best) {
    __shared__ float eg[32 * 257];  // stride 257: lane-per-code reads conflict-free
    __shared__ float zs[8][256];
    __shared__ ushort rid[8];
    __shared__ float arow[8];
    const int g = blockIdx.x;
    const int t = threadIdx.x;
#pragma unroll
    for (int i = 0; i < 8; ++i) {
        int f = t + i * 256;  // 32 codes x 64 float4
        int c = f >> 6, k4 = f & 63;
        float4 v = *(const float4*)(emb + (size_t)(g * 32 + c) * 256 + k4 * 4);
        float* dst = eg + c * 257 + k4 * 4;
        dst[0] = v.x; dst[1] = v.y; dst[2] = v.z; dst[3] = v.w;
    }
    const int cnt = (int)gcnt[g];
    for (int base = 0; base < cnt; base += 8) {
        __syncthreads();
        if (t < 8) {
            int i = base + t;
            if (i < cnt) {
                ushort r = bucket[(size_t)g * NROWS + i];
                rid[t] = r;
                arow[t] = zn[r];
            } else {
                rid[t] = 0xFFFF;
            }
        }
        __syncthreads();
#pragma unroll
        for (int i = 0; i < 2; ++i) {
            int f = t + i * 256;
            int s = f >> 6, k4 = f & 63;
            if (rid[s] != 0xFFFF)
                *(float4*)(&zs[s][k4 * 4]) =
                    *(const float4*)(zf32 + (size_t)rid[s] * 256 + k4 * 4);
        }
        __syncthreads();
        const int lane = t & 63, w = t >> 6;
        const int slot = w * 2 + (lane >> 5);
        const int code = lane & 31;
        if (rid[slot] != 0xFFFF) {
            const float* zr = zs[slot];
            const float* er = eg + code * 257;
            float acc = 0.f;
#pragma unroll 8
            for (int k = 0; k < 256; ++k) acc = fmaf(zr[k], er[k], acc);
            float d = arow[slot] - 2.f * acc;  // same bits as round-2 kernel
            unsigned fb = __float_as_uint(d);
            fb ^= (fb & 0x80000000u) ? 0xFFFFFFFFu : 0x80000000u;
            unsigned long long pk =
                ((unsigned long long)fb << 32) | (unsigned)(g * 32 + code);
#pragma unroll
            for (int m = 1; m < 32; m <<= 1) {
                unsigned long long o = __shfl_xor(pk, m, 64);
                if (o < pk) pk = o;
            }
            if ((lane & 31) == 0) atomicMin(&best[rid[slot]], pk);
        }
    }
}

// ---- kernel 5c: unpack best -> bestidx + oidx ----
__global__ void k_widx(const unsigned long long* __restrict__ best,
                       int* __restrict__ bestidx, float* __restrict__ oidx) {
    int n = blockIdx.x * 256 + threadIdx.x;
    int bi = (int)(unsigned)(best[n] & 0xFFFFFFFFull);
    bestidx[n] = bi;
    oidx[n] = (float)bi;
}

// ---- kernel 6: gather z_q + loss, 64 rows/block, 1 atomic/block ----
__global__ __launch_bounds__(256) void k_gather(
    const float* __restrict__ z, const float* __restrict__ emb,
    const int* __restrict__ bestidx, float* __restrict__ zq,
    float* __restrict__ loss) {
    __shared__ float eg[64][257];  // [row][c], pad: c-major read is 2-lanes/bank
    __shared__ float lsum[4];
    const int t = threadIdx.x;
    const int n0 = blockIdx.x * 64;
    const int b = n0 >> 10, hw0 = n0 & 1023;  // 64 rows never straddle b
    // stage 64 gathered emb rows: 4 threads per row, 64-f chunks (coalesced 256B)
    {
        const int row = t >> 2;
        const int cbase = (t & 3) * 64;
        const int code = bestidx[n0 + row];
        const float* er = emb + (size_t)code * 256 + cbase;
        float* dst = &eg[row][cbase];
#pragma unroll
        for (int i = 0; i < 16; ++i) {
            float4 v = *(const float4*)(er + i * 4);
            dst[i * 4 + 0] = v.x; dst[i * 4 + 1] = v.y;
            dst[i * 4 + 2] = v.z; dst[i * 4 + 3] = v.w;
        }
    }
    __syncthreads();
    const int w = t >> 6, lane = t & 63;
    float acc = 0.f;
    const size_t obase = (size_t)b * 262144 + hw0 + lane;
#pragma unroll 4
    for (int ci = 0; ci < 64; ++ci) {
        int c = w * 64 + ci;
        float e = eg[lane][c];
        size_t off = obase + (size_t)c * 1024;
        float zv = z[off];
        zq[off] = e;
        float d = e - zv;
        acc = fmaf(d, d, acc);
    }
#pragma unroll
    for (int m = 32; m; m >>= 1) acc += __shfl_xor(acc, m, 64);
    if (lane == 0) lsum[w] = acc;
    __syncthreads();
    if (t == 0) {
        float s = (lsum[0] + lsum[1]) + (lsum[2] + lsum[3]);
        atomicAdd(loss, s * (2.f / 4194304.f));
    }
}

extern "C" void kernel_launch(void* const* d_in, const int* in_sizes, int n_in,
                              void* d_out, int out_size, void* d_ws, size_t ws_size,
                              hipStream_t stream) {
    const float* z = (const float*)d_in[0];
    const float* emb = (const float*)d_in[1];
    float* out = (float*)d_out;
    float* zq = out;
    float* loss = out + 4194304;
    float* oidx = out + 4194305;
    float* zf32 = out;  // zq region doubles as transposed-z scratch until k_gather

    ushort* z16 = (ushort*)d_ws;               // 8 MB; dead after k_coarse
    ushort* e16 = z16 + 4194304;               // 4 MB
    ushort* tbl = e16 + 2097152;               // 8 MB [n][256] f16
    float* zn = (float*)(tbl + 4194304);       // 64 KB
    int* bestidx = (int*)(zn + 16384);         // 64 KB
    unsigned long long* best = (unsigned long long*)(bestidx + 16384);  // 128 KB
    unsigned* gcnt = (unsigned*)(best + 16384);                          // 1 KB
    ushort* bucket = z16;                      // alias dead z16 (exactly 8 MB)

    hipMemsetAsync(loss, 0, sizeof(float), stream);
    hipMemsetAsync(gcnt, 0, 256 * sizeof(unsigned), stream);
    hipMemsetAsync(best, 0xFF, NROWS * sizeof(unsigned long long), stream);
    k_cvt_z<<<dim3(16, 4, 4), dim3(256), 0, stream>>>(z, zf32, z16);
    k_cvt_e<<<dim3(2048), dim3(256), 0, stream>>>(emb, e16);
    k_znorm<<<dim3(NROWS / 256), dim3(256), 0, stream>>>(z, zn);
    k_coarse<<<dim3(NROWS / 128, NCODES / 128), dim3(256), 0, stream>>>(z16, e16, tbl);
    k_flag<<<dim3(NROWS / 4), dim3(256), 0, stream>>>(tbl, bucket, gcnt);
    k_rescore2<<<dim3(256), dim3(256), 0, stream>>>(zf32, emb, zn, bucket, gcnt, best);
    k_widx<<<dim3(NROWS / 256), dim3(256), 0, stream>>>(best, bestidx, oidx);
    k_gather<<<dim3(NROWS / 64), dim3(256), 0, stream>>>(z, emb, bestidx, zq, loss);
}

// Round 8
// 303.156 us; speedup vs baseline: 3.7570x; 1.1870x over previous
//
#include <hip/hip_runtime.h>
#include <hip/hip_fp16.h>
#include <float.h>

#define K_DIM 256
#define HW1 1024
#define NROWS 16384
#define NCODES 8192

typedef __attribute__((ext_vector_type(8))) short bf16x8;
typedef __attribute__((ext_vector_type(4))) float f32x4;

__device__ __forceinline__ ushort bf16rn(float x) {
    unsigned u = __float_as_uint(x);
    return (ushort)((u + 0x7FFFu + ((u >> 16) & 1u)) >> 16);
}

__device__ __forceinline__ void gl16(const void* g, void* l) {
    __builtin_amdgcn_global_load_lds((const __attribute__((address_space(1))) void*)g,
                                     (__attribute__((address_space(3))) void*)l, 16, 0, 0);
}

// ---- kernel 1: z [b][k][hw] -> zf32/z16 [n][k] + FUSED exact znorm ----
// LDS [hw][k] pitch 257: stage-in 2-way, write-out 2-way (stride-64 lanes),
// znorm thread-per-row 2-way — all conflict-free tiers.
__global__ __launch_bounds__(256) void k_cvt_z(const float* __restrict__ z,
                                               float* __restrict__ zf32,
                                               ushort* __restrict__ z16,
                                               float* __restrict__ zn) {
    __shared__ float ls[64 * 257];
    const int b = blockIdx.x >> 4, hw0 = (blockIdx.x & 15) * 64;
    const int t = threadIdx.x;
    const float* src = z + (size_t)b * 262144 + hw0;
    // stage 256k x 64hw, transposing to [hw][k]
#pragma unroll
    for (int i = 0; i < 16; ++i) {
        int f = t + i * 256;
        int kl = f >> 4, c4 = f & 15;  // k row, hw-quad
        float4 v = *(const float4*)(src + (size_t)kl * 1024 + c4 * 4);
        ls[(c4 * 4 + 0) * 257 + kl] = v.x;
        ls[(c4 * 4 + 1) * 257 + kl] = v.y;
        ls[(c4 * 4 + 2) * 257 + kl] = v.z;
        ls[(c4 * 4 + 3) * 257 + kl] = v.w;
    }
    __syncthreads();
    // write-out: one row per wave per iter; lanes cover floats cl, cl+64, ...
    {
        const int w = t >> 6, cl = t & 63;
#pragma unroll
        for (int i = 0; i < 16; ++i) {
            int r = i * 4 + w;
            const float* lr = ls + r * 257;
            int n = b * 1024 + hw0 + r;
            float* od = zf32 + (size_t)n * 256;
            ushort* oh = z16 + (size_t)n * 256;
#pragma unroll
            for (int j = 0; j < 4; ++j) {
                float x = lr[cl + 64 * j];
                od[cl + 64 * j] = x;
                oh[cl + 64 * j] = bf16rn(x);
            }
        }
    }
    // fused znorm: numpy pairwise order, bit-identical to round-2 k_znorm
    if (t < 64) {
        const int r = t;
        const float* lr = ls + r * 257;
        float half[2];
#pragma unroll
        for (int h = 0; h < 2; ++h) {
            float rj[8];
#pragma unroll
            for (int j = 0; j < 8; ++j) {
                float v = lr[h * 128 + j];
                float s = v * v;
                asm volatile("" : "+v"(s));
                rj[j] = s;
            }
#pragma unroll
            for (int i = 1; i < 16; ++i) {
#pragma unroll
                for (int j = 0; j < 8; ++j) {
                    float v = lr[h * 128 + 8 * i + j];
                    float s = v * v;
                    asm volatile("" : "+v"(s));
                    rj[j] += s;
                }
            }
            half[h] = ((rj[0] + rj[1]) + (rj[2] + rj[3])) +
                      ((rj[4] + rj[5]) + (rj[6] + rj[7]));
        }
        zn[b * 1024 + hw0 + r] = half[0] + half[1];
    }
}

// ---- kernel 2: emb fp32 -> bf16; block 0 also inits gcnt + loss ----
__global__ void k_cvt_e(const float* __restrict__ emb, ushort* __restrict__ e16,
                        unsigned* __restrict__ gcnt, float* __restrict__ loss) {
    if (blockIdx.x == 0) {
        gcnt[threadIdx.x] = 0u;
        if (threadIdx.x == 0) *loss = 0.f;
    }
    int f = blockIdx.x * 256 + threadIdx.x;
    float4 v = *(const float4*)(emb + (size_t)f * 4);
    ushort4 h;
    h.x = bf16rn(v.x); h.y = bf16rn(v.y); h.z = bf16rn(v.z); h.w = bf16rn(v.w);
    *(ushort4*)(e16 + (size_t)f * 4) = h;
}

// ---- kernel 3: bf16 MFMA coarse pass (unchanged from round 7) ----
__global__ __launch_bounds__(256, 2) void k_coarse(
    const ushort* __restrict__ z16, const ushort* __restrict__ e16,
    ushort* __restrict__ tbl) {
    __shared__ char smem[32768];
    char* As = smem;
    char* Bs = smem + 16384;
    const int tid = threadIdx.x;
    const int w = tid >> 6, lane = tid & 63;
    const int tx = lane & 15, q = lane >> 4;
    const int row0 = blockIdx.x * 128, c0 = blockIdx.y * 128;

    f32x4 acc[4][4];
#pragma unroll
    for (int mi = 0; mi < 4; ++mi)
#pragma unroll
        for (int ni = 0; ni < 4; ++ni) acc[mi][ni] = (f32x4){0.f, 0.f, 0.f, 0.f};

    for (int k0 = 0; k0 < K_DIM; k0 += 64) {
#pragma unroll
        for (int j = 0; j < 4; ++j) {
            int r = (w * 4 + j) * 8 + (lane >> 3);
            int c = (lane & 7) ^ (r & 7);  // inverse swizzle on global side
            gl16(z16 + (((size_t)(row0 + r)) << 8) + k0 + (c << 3),
                 As + (w * 4 + j) * 1024);
            gl16(e16 + (((size_t)(c0 + r)) << 8) + k0 + (c << 3),
                 Bs + (w * 4 + j) * 1024);
        }
        __syncthreads();
#pragma unroll
        for (int ks = 0; ks < 2; ++ks) {
            int cd = ks * 4;
            const int rAb = (w & 1) * 64, rBb = (w >> 1) * 64;
            bf16x8 af[4], bfv[4];
#pragma unroll
            for (int mi = 0; mi < 4; ++mi)
                af[mi] = *(const bf16x8*)(As + (rAb + mi * 16 + tx) * 128 +
                                          (((cd + q) ^ (tx & 7)) << 4));
#pragma unroll
            for (int ni = 0; ni < 4; ++ni)
                bfv[ni] = *(const bf16x8*)(Bs + (rBb + ni * 16 + tx) * 128 +
                                           (((cd + q) ^ (tx & 7)) << 4));
#pragma unroll
            for (int mi = 0; mi < 4; ++mi)
#pragma unroll
                for (int ni = 0; ni < 4; ++ni)
                    acc[mi][ni] = __builtin_amdgcn_mfma_f32_16x16x32_bf16(
                        af[mi], bfv[ni], acc[mi][ni], 0, 0, 0);
        }
        __syncthreads();
    }

    ushort* tb = (ushort*)smem;  // [128][4]
    const int rAb = (w & 1) * 64;
#pragma unroll
    for (int g = 0; g < 2; ++g) {
        int gcol = (w >> 1) * 2 + g;
#pragma unroll
        for (int mi = 0; mi < 4; ++mi) {
            float mv[4];
#pragma unroll
            for (int e = 0; e < 4; ++e)
                mv[e] = fmaxf(acc[mi][2 * g][e], acc[mi][2 * g + 1][e]);
#pragma unroll
            for (int msk = 1; msk < 16; msk <<= 1)
#pragma unroll
                for (int e = 0; e < 4; ++e)
                    mv[e] = fmaxf(mv[e], __shfl_xor(mv[e], msk, 64));
            if (tx == 0) {
                int rl = rAb + mi * 16 + q * 4;
#pragma unroll
                for (int e = 0; e < 4; ++e)
                    tb[(rl + e) * 4 + gcol] = __half_as_ushort(__float2half(mv[e]));
            }
        }
    }
    __syncthreads();
    if (tid < 128) {
        ushort4 v = *(ushort4*)(tb + tid * 4);
        *(ushort4*)(tbl + (size_t)(row0 + tid) * 256 + blockIdx.y * 4) = v;
    }
}

// ---- kernel 4: flag pass — bucket rows by candidate group; init best ----
__global__ void k_flag(const ushort* __restrict__ tbl, ushort* __restrict__ bucket,
                       unsigned* __restrict__ gcnt,
                       unsigned long long* __restrict__ best) {
    const int wid = threadIdx.x >> 6, lane = threadIdx.x & 63;
    const int n = blockIdx.x * 4 + wid;
    if (lane == 0) best[n] = 0xFFFFFFFFFFFFFFFFull;  // before k_rescore2 (stream order)
    ushort4 raw = *(const ushort4*)(tbl + (size_t)n * 256 + lane * 4);
    float gm[4];
    gm[0] = __half2float(__ushort_as_half(raw.x));
    gm[1] = __half2float(__ushort_as_half(raw.y));
    gm[2] = __half2float(__ushort_as_half(raw.z));
    gm[3] = __half2float(__ushort_as_half(raw.w));
    float gmax = fmaxf(fmaxf(gm[0], gm[1]), fmaxf(gm[2], gm[3]));
#pragma unroll
    for (int m = 1; m < 64; m <<= 1) gmax = fmaxf(gmax, __shfl_xor(gmax, m, 64));
    const float th = gmax - 1.0e-4f;  // provable capture margin
#pragma unroll
    for (int i = 0; i < 4; ++i) {
        if (gm[i] >= th) {
            int g = lane * 4 + i;
            unsigned pos = atomicAdd(&gcnt[g], 1u);
            bucket[(size_t)g * NROWS + pos] = (ushort)n;
        }
    }
}

// ---- kernel 5: exact rescore, one block per group (unchanged) ----
__global__ __launch_bounds__(256) void k_rescore2(
    const float* __restrict__ zf32, const float* __restrict__ emb,
    const float* __restrict__ zn, const ushort* __restrict__ bucket,
    const unsigned* __restrict__ gcnt, unsigned long long* __restrict__ best) {
    __shared__ float eg[32 * 257];
    __shared__ float zs[8][256];
    __shared__ ushort rid[8];
    __shared__ float arow[8];
    const int g = blockIdx.x;
    const int t = threadIdx.x;
#pragma unroll
    for (int i = 0; i < 8; ++i) {
        int f = t + i * 256;
        int c = f >> 6, k4 = f & 63;
        float4 v = *(const float4*)(emb + (size_t)(g * 32 + c) * 256 + k4 * 4);
        float* dst = eg + c * 257 + k4 * 4;
        dst[0] = v.x; dst[1] = v.y; dst[2] = v.z; dst[3] = v.w;
    }
    const int cnt = (int)gcnt[g];
    for (int base = 0; base < cnt; base += 8) {
        __syncthreads();
        if (t < 8) {
            int i = base + t;
            if (i < cnt) {
                ushort r = bucket[(size_t)g * NROWS + i];
                rid[t] = r;
                arow[t] = zn[r];
            } else {
                rid[t] = 0xFFFF;
            }
        }
        __syncthreads();
#pragma unroll
        for (int i = 0; i < 2; ++i) {
            int f = t + i * 256;
            int s = f >> 6, k4 = f & 63;
            if (rid[s] != 0xFFFF)
                *(float4*)(&zs[s][k4 * 4]) =
                    *(const float4*)(zf32 + (size_t)rid[s] * 256 + k4 * 4);
        }
        __syncthreads();
        const int lane = t & 63, w = t >> 6;
        const int slot = w * 2 + (lane >> 5);
        const int code = lane & 31;
        if (rid[slot] != 0xFFFF) {
            const float* zr = zs[slot];
            const float* er = eg + code * 257;
            float acc = 0.f;
#pragma unroll 8
            for (int k = 0; k < 256; ++k) acc = fmaf(zr[k], er[k], acc);
            float d = arow[slot] - 2.f * acc;  // same bits as round-2 kernel
            unsigned fb = __float_as_uint(d);
            fb ^= (fb & 0x80000000u) ? 0xFFFFFFFFu : 0x80000000u;
            unsigned long long pk =
                ((unsigned long long)fb << 32) | (unsigned)(g * 32 + code);
#pragma unroll
            for (int m = 1; m < 32; m <<= 1) {
                unsigned long long o = __shfl_xor(pk, m, 64);
                if (o < pk) pk = o;
            }
            if ((lane & 31) == 0) atomicMin(&best[rid[slot]], pk);
        }
    }
}

// ---- kernel 6: gather z_q + loss + oidx (widx fused), 1 atomic/block ----
__global__ __launch_bounds__(256) void k_gather(
    const float* __restrict__ z, const float* __restrict__ emb,
    const unsigned long long* __restrict__ best, float* __restrict__ zq,
    float* __restrict__ oidx, float* __restrict__ loss) {
    __shared__ float eg[64][257];
    __shared__ float lsum[4];
    const int t = threadIdx.x;
    const int n0 = blockIdx.x * 64;
    const int b = n0 >> 10, hw0 = n0 & 1023;
    {
        const int row = t >> 2;
        const int cbase = (t & 3) * 64;
        const int code = (int)(unsigned)(best[n0 + row] & 0xFFFFFFFFull);
        if ((t & 3) == 0) oidx[n0 + row] = (float)code;
        const float* er = emb + (size_t)code * 256 + cbase;
        float* dst = &eg[row][cbase];
#pragma unroll
        for (int i = 0; i < 16; ++i) {
            float4 v = *(const float4*)(er + i * 4);
            dst[i * 4 + 0] = v.x; dst[i * 4 + 1] = v.y;
            dst[i * 4 + 2] = v.z; dst[i * 4 + 3] = v.w;
        }
    }
    __syncthreads();
    const int w = t >> 6, lane = t & 63;
    float acc = 0.f;
    const size_t obase = (size_t)b * 262144 + hw0 + lane;
#pragma unroll 4
    for (int ci = 0; ci < 64; ++ci) {
        int c = w * 64 + ci;
        float e = eg[lane][c];
        size_t off = obase + (size_t)c * 1024;
        float zv = z[off];
        zq[off] = e;
        float d = e - zv;
        acc = fmaf(d, d, acc);
    }
#pragma unroll
    for (int m = 32; m; m >>= 1) acc += __shfl_xor(acc, m, 64);
    if (lane == 0) lsum[w] = acc;
    __syncthreads();
    if (t == 0) {
        float s = (lsum[0] + lsum[1]) + (lsum[2] + lsum[3]);
        atomicAdd(loss, s * (2.f / 4194304.f));
    }
}

extern "C" void kernel_launch(void* const* d_in, const int* in_sizes, int n_in,
                              void* d_out, int out_size, void* d_ws, size_t ws_size,
                              hipStream_t stream) {
    const float* z = (const float*)d_in[0];
    const float* emb = (const float*)d_in[1];
    float* out = (float*)d_out;
    float* zq = out;
    float* loss = out + 4194304;
    float* oidx = out + 4194305;
    float* zf32 = out;  // zq region doubles as transposed-z scratch until k_gather

    ushort* z16 = (ushort*)d_ws;               // 8 MB; dead after k_coarse
    ushort* e16 = z16 + 4194304;               // 4 MB
    ushort* tbl = e16 + 2097152;               // 8 MB [n][256] f16
    float* zn = (float*)(tbl + 4194304);       // 64 KB
    unsigned long long* best = (unsigned long long*)(zn + 16384);  // 128 KB
    unsigned* gcnt = (unsigned*)(best + 16384);                    // 1 KB
    ushort* bucket = z16;                      // alias dead z16 (exactly 8 MB)

    k_cvt_z<<<dim3(256), dim3(256), 0, stream>>>(z, zf32, z16, zn);
    k_cvt_e<<<dim3(2048), dim3(256), 0, stream>>>(emb, e16, gcnt, loss);
    k_coarse<<<dim3(NROWS / 128, NCODES / 128), dim3(256), 0, stream>>>(z16, e16, tbl);
    k_flag<<<dim3(NROWS / 4), dim3(256), 0, stream>>>(tbl, bucket, gcnt, best);
    k_rescore2<<<dim3(256), dim3(256), 0, stream>>>(zf32, emb, zn, bucket, gcnt, best);
    k_gather<<<dim3(NROWS / 64), dim3(256), 0, stream>>>(z, emb, best, zq, oidx, loss);
}

// Round 9
// 295.708 us; speedup vs baseline: 3.8516x; 1.0252x over previous
//
#include <hip/hip_runtime.h>
#include <hip/hip_fp16.h>
#include <float.h>

#define K_DIM 256
#define HW1 1024
#define NROWS 16384
#define NCODES 8192

typedef __attribute__((ext_vector_type(8))) short bf16x8;
typedef __attribute__((ext_vector_type(4))) float f32x4;

__device__ __forceinline__ ushort bf16rn(float x) {
    unsigned u = __float_as_uint(x);
    return (ushort)((u + 0x7FFFu + ((u >> 16) & 1u)) >> 16);
}

__device__ __forceinline__ void gl16(const void* g, void* l) {
    __builtin_amdgcn_global_load_lds((const __attribute__((address_space(1))) void*)g,
                                     (__attribute__((address_space(3))) void*)l, 16, 0, 0);
}

// ---- kernel 1: z [b][k][hw] -> zf32/z16 [n][k] + FUSED exact znorm ----
__global__ __launch_bounds__(256) void k_cvt_z(const float* __restrict__ z,
                                               float* __restrict__ zf32,
                                               ushort* __restrict__ z16,
                                               float* __restrict__ zn) {
    __shared__ float ls[64 * 257];
    const int b = blockIdx.x >> 4, hw0 = (blockIdx.x & 15) * 64;
    const int t = threadIdx.x;
    const float* src = z + (size_t)b * 262144 + hw0;
#pragma unroll
    for (int i = 0; i < 16; ++i) {
        int f = t + i * 256;
        int kl = f >> 4, c4 = f & 15;
        float4 v = *(const float4*)(src + (size_t)kl * 1024 + c4 * 4);
        ls[(c4 * 4 + 0) * 257 + kl] = v.x;
        ls[(c4 * 4 + 1) * 257 + kl] = v.y;
        ls[(c4 * 4 + 2) * 257 + kl] = v.z;
        ls[(c4 * 4 + 3) * 257 + kl] = v.w;
    }
    __syncthreads();
    {
        const int w = t >> 6, cl = t & 63;
#pragma unroll
        for (int i = 0; i < 16; ++i) {
            int r = i * 4 + w;
            const float* lr = ls + r * 257;
            int n = b * 1024 + hw0 + r;
            float* od = zf32 + (size_t)n * 256;
            ushort* oh = z16 + (size_t)n * 256;
#pragma unroll
            for (int j = 0; j < 4; ++j) {
                float x = lr[cl + 64 * j];
                od[cl + 64 * j] = x;
                oh[cl + 64 * j] = bf16rn(x);
            }
        }
    }
    if (t < 64) {
        const int r = t;
        const float* lr = ls + r * 257;
        float half[2];
#pragma unroll
        for (int h = 0; h < 2; ++h) {
            float rj[8];
#pragma unroll
            for (int j = 0; j < 8; ++j) {
                float v = lr[h * 128 + j];
                float s = v * v;
                asm volatile("" : "+v"(s));
                rj[j] = s;
            }
#pragma unroll
            for (int i = 1; i < 16; ++i) {
#pragma unroll
                for (int j = 0; j < 8; ++j) {
                    float v = lr[h * 128 + 8 * i + j];
                    float s = v * v;
                    asm volatile("" : "+v"(s));
                    rj[j] += s;
                }
            }
            half[h] = ((rj[0] + rj[1]) + (rj[2] + rj[3])) +
                      ((rj[4] + rj[5]) + (rj[6] + rj[7]));
        }
        zn[b * 1024 + hw0 + r] = half[0] + half[1];
    }
}

// ---- kernel 2: emb fp32 -> bf16; block 0 also inits gcnt + loss ----
__global__ void k_cvt_e(const float* __restrict__ emb, ushort* __restrict__ e16,
                        unsigned* __restrict__ gcnt, float* __restrict__ loss) {
    if (blockIdx.x == 0) {
        gcnt[threadIdx.x] = 0u;
        if (threadIdx.x == 0) *loss = 0.f;
    }
    int f = blockIdx.x * 256 + threadIdx.x;
    float4 v = *(const float4*)(emb + (size_t)f * 4);
    ushort4 h;
    h.x = bf16rn(v.x); h.y = bf16rn(v.y); h.z = bf16rn(v.z); h.w = bf16rn(v.w);
    *(ushort4*)(e16 + (size_t)f * 4) = h;
}

// ---- kernel 3: bf16 MFMA coarse pass, tile 128x256, wave-tile 64x128 ----
// ds_read/MFMA = 0.375; 48 KB LDS -> 3 blocks/CU; half the blocks/barriers
// of the round-8 version. Layout identical to verified 16x16x32 scheme.
__global__ __launch_bounds__(256) void k_coarse(
    const ushort* __restrict__ z16, const ushort* __restrict__ e16,
    ushort* __restrict__ tbl) {
    __shared__ char smem[49152];
    char* As = smem;            // [128][64] bf16, chunk-swizzled, 16 KB
    char* Bs = smem + 16384;    // [256][64] bf16, chunk-swizzled, 32 KB
    const int tid = threadIdx.x;
    const int w = tid >> 6, lane = tid & 63;
    const int tx = lane & 15, q = lane >> 4;
    const int row0 = blockIdx.x * 128, c0 = blockIdx.y * 256;
    const int Am = (w & 1) * 64;    // wave M offset
    const int Bn = (w >> 1) * 128;  // wave N offset

    f32x4 acc[4][8];
#pragma unroll
    for (int mi = 0; mi < 4; ++mi)
#pragma unroll
        for (int ni = 0; ni < 8; ++ni) acc[mi][ni] = (f32x4){0.f, 0.f, 0.f, 0.f};

    for (int k0 = 0; k0 < K_DIM; k0 += 64) {
#pragma unroll
        for (int j = 0; j < 4; ++j) {  // A: 128 rows, 4 gl16/wave
            int r = (w * 4 + j) * 8 + (lane >> 3);
            int c = (lane & 7) ^ (r & 7);
            gl16(z16 + (((size_t)(row0 + r)) << 8) + k0 + (c << 3),
                 As + (w * 4 + j) * 1024);
        }
#pragma unroll
        for (int j = 0; j < 8; ++j) {  // B: 256 rows, 8 gl16/wave
            int r = (w * 8 + j) * 8 + (lane >> 3);
            int c = (lane & 7) ^ (r & 7);
            gl16(e16 + (((size_t)(c0 + r)) << 8) + k0 + (c << 3),
                 Bs + (w * 8 + j) * 1024);
        }
        __syncthreads();
#pragma unroll
        for (int ks = 0; ks < 2; ++ks) {
            int cd = ks * 4;
            bf16x8 af[4], bfv[8];
#pragma unroll
            for (int mi = 0; mi < 4; ++mi)
                af[mi] = *(const bf16x8*)(As + (Am + mi * 16 + tx) * 128 +
                                          (((cd + q) ^ (tx & 7)) << 4));
#pragma unroll
            for (int ni = 0; ni < 8; ++ni)
                bfv[ni] = *(const bf16x8*)(Bs + (Bn + ni * 16 + tx) * 128 +
                                           (((cd + q) ^ (tx & 7)) << 4));
#pragma unroll
            for (int mi = 0; mi < 4; ++mi)
#pragma unroll
                for (int ni = 0; ni < 8; ++ni)
                    acc[mi][ni] = __builtin_amdgcn_mfma_f32_16x16x32_bf16(
                        af[mi], bfv[ni], acc[mi][ni], 0, 0, 0);
        }
        __syncthreads();
    }

    // epilogue: per row, max over each 32-col group; tb aliases As (safe: last
    // barrier above drained all frag reads)
    ushort* tb = (ushort*)smem;  // [128][8]
#pragma unroll
    for (int g = 0; g < 4; ++g) {
        int gcol = (w >> 1) * 4 + g;
#pragma unroll
        for (int mi = 0; mi < 4; ++mi) {
            float mv[4];
#pragma unroll
            for (int e = 0; e < 4; ++e)
                mv[e] = fmaxf(acc[mi][2 * g][e], acc[mi][2 * g + 1][e]);
#pragma unroll
            for (int msk = 1; msk < 16; msk <<= 1)
#pragma unroll
                for (int e = 0; e < 4; ++e)
                    mv[e] = fmaxf(mv[e], __shfl_xor(mv[e], msk, 64));
            if (tx == 0) {
                int rl = Am + mi * 16 + q * 4;
#pragma unroll
                for (int e = 0; e < 4; ++e)
                    tb[(rl + e) * 8 + gcol] = __half_as_ushort(__float2half(mv[e]));
            }
        }
    }
    __syncthreads();
    if (tid < 128) {
        ushort4 v0 = *(ushort4*)(tb + tid * 8);
        ushort4 v1 = *(ushort4*)(tb + tid * 8 + 4);
        ushort* dst = tbl + (size_t)(row0 + tid) * 256 + blockIdx.y * 8;
        *(ushort4*)(dst) = v0;
        *(ushort4*)(dst + 4) = v1;
    }
}

// ---- kernel 4: flag pass — bucket rows by candidate group; init best ----
__global__ void k_flag(const ushort* __restrict__ tbl, ushort* __restrict__ bucket,
                       unsigned* __restrict__ gcnt,
                       unsigned long long* __restrict__ best) {
    const int wid = threadIdx.x >> 6, lane = threadIdx.x & 63;
    const int n = blockIdx.x * 4 + wid;
    if (lane == 0) best[n] = 0xFFFFFFFFFFFFFFFFull;
    ushort4 raw = *(const ushort4*)(tbl + (size_t)n * 256 + lane * 4);
    float gm[4];
    gm[0] = __half2float(__ushort_as_half(raw.x));
    gm[1] = __half2float(__ushort_as_half(raw.y));
    gm[2] = __half2float(__ushort_as_half(raw.z));
    gm[3] = __half2float(__ushort_as_half(raw.w));
    float gmax = fmaxf(fmaxf(gm[0], gm[1]), fmaxf(gm[2], gm[3]));
#pragma unroll
    for (int m = 1; m < 64; m <<= 1) gmax = fmaxf(gmax, __shfl_xor(gmax, m, 64));
    const float th = gmax - 1.0e-4f;
#pragma unroll
    for (int i = 0; i < 4; ++i) {
        if (gm[i] >= th) {
            int g = lane * 4 + i;
            unsigned pos = atomicAdd(&gcnt[g], 1u);
            bucket[(size_t)g * NROWS + pos] = (ushort)n;
        }
    }
}

// ---- kernel 5: exact rescore, one block per group ----
__global__ __launch_bounds__(256) void k_rescore2(
    const float* __restrict__ zf32, const float* __restrict__ emb,
    const float* __restrict__ zn, const ushort* __restrict__ bucket,
    const unsigned* __restrict__ gcnt, unsigned long long* __restrict__ best) {
    __shared__ float eg[32 * 257];
    __shared__ float zs[8][256];
    __shared__ ushort rid[8];
    __shared__ float arow[8];
    const int g = blockIdx.x;
    const int t = threadIdx.x;
#pragma unroll
    for (int i = 0; i < 8; ++i) {
        int f = t + i * 256;
        int c = f >> 6, k4 = f & 63;
        float4 v = *(const float4*)(emb + (size_t)(g * 32 + c) * 256 + k4 * 4);
        float* dst = eg + c * 257 + k4 * 4;
        dst[0] = v.x; dst[1] = v.y; dst[2] = v.z; dst[3] = v.w;
    }
    const int cnt = (int)gcnt[g];
    for (int base = 0; base < cnt; base += 8) {
        __syncthreads();
        if (t < 8) {
            int i = base + t;
            if (i < cnt) {
                ushort r = bucket[(size_t)g * NROWS + i];
                rid[t] = r;
                arow[t] = zn[r];
            } else {
                rid[t] = 0xFFFF;
            }
        }
        __syncthreads();
#pragma unroll
        for (int i = 0; i < 2; ++i) {
            int f = t + i * 256;
            int s = f >> 6, k4 = f & 63;
            if (rid[s] != 0xFFFF)
                *(float4*)(&zs[s][k4 * 4]) =
                    *(const float4*)(zf32 + (size_t)rid[s] * 256 + k4 * 4);
        }
        __syncthreads();
        const int lane = t & 63, w = t >> 6;
        const int slot = w * 2 + (lane >> 5);
        const int code = lane & 31;
        if (rid[slot] != 0xFFFF) {
            const float* zr = zs[slot];
            const float* er = eg + code * 257;
            float acc = 0.f;
#pragma unroll 8
            for (int k = 0; k < 256; ++k) acc = fmaf(zr[k], er[k], acc);
            float d = arow[slot] - 2.f * acc;
            unsigned fb = __float_as_uint(d);
            fb ^= (fb & 0x80000000u) ? 0xFFFFFFFFu : 0x80000000u;
            unsigned long long pk =
                ((unsigned long long)fb << 32) | (unsigned)(g * 32 + code);
#pragma unroll
            for (int m = 1; m < 32; m <<= 1) {
                unsigned long long o = __shfl_xor(pk, m, 64);
                if (o < pk) pk = o;
            }
            if ((lane & 31) == 0) atomicMin(&best[rid[slot]], pk);
        }
    }
}

// ---- kernel 6: gather z_q + loss + oidx, 1 atomic/block ----
__global__ __launch_bounds__(256) void k_gather(
    const float* __restrict__ z, const float* __restrict__ emb,
    const unsigned long long* __restrict__ best, float* __restrict__ zq,
    float* __restrict__ oidx, float* __restrict__ loss) {
    __shared__ float eg[64][257];
    __shared__ float lsum[4];
    const int t = threadIdx.x;
    const int n0 = blockIdx.x * 64;
    const int b = n0 >> 10, hw0 = n0 & 1023;
    {
        const int row = t >> 2;
        const int cbase = (t & 3) * 64;
        const int code = (int)(unsigned)(best[n0 + row] & 0xFFFFFFFFull);
        if ((t & 3) == 0) oidx[n0 + row] = (float)code;
        const float* er = emb + (size_t)code * 256 + cbase;
        float* dst = &eg[row][cbase];
#pragma unroll
        for (int i = 0; i < 16; ++i) {
            float4 v = *(const float4*)(er + i * 4);
            dst[i * 4 + 0] = v.x; dst[i * 4 + 1] = v.y;
            dst[i * 4 + 2] = v.z; dst[i * 4 + 3] = v.w;
        }
    }
    __syncthreads();
    const int w = t >> 6, lane = t & 63;
    float acc = 0.f;
    const size_t obase = (size_t)b * 262144 + hw0 + lane;
#pragma unroll 4
    for (int ci = 0; ci < 64; ++ci) {
        int c = w * 64 + ci;
        float e = eg[lane][c];
        size_t off = obase + (size_t)c * 1024;
        float zv = z[off];
        zq[off] = e;
        float d = e - zv;
        acc = fmaf(d, d, acc);
    }
#pragma unroll
    for (int m = 32; m; m >>= 1) acc += __shfl_xor(acc, m, 64);
    if (lane == 0) lsum[w] = acc;
    __syncthreads();
    if (t == 0) {
        float s = (lsum[0] + lsum[1]) + (lsum[2] + lsum[3]);
        atomicAdd(loss, s * (2.f / 4194304.f));
    }
}

extern "C" void kernel_launch(void* const* d_in, const int* in_sizes, int n_in,
                              void* d_out, int out_size, void* d_ws, size_t ws_size,
                              hipStream_t stream) {
    const float* z = (const float*)d_in[0];
    const float* emb = (const float*)d_in[1];
    float* out = (float*)d_out;
    float* zq = out;
    float* loss = out + 4194304;
    float* oidx = out + 4194305;
    float* zf32 = out;  // zq region doubles as transposed-z scratch until k_gather

    ushort* z16 = (ushort*)d_ws;               // 8 MB; dead after k_coarse
    ushort* e16 = z16 + 4194304;               // 4 MB
    ushort* tbl = e16 + 2097152;               // 8 MB [n][256] f16
    float* zn = (float*)(tbl + 4194304);       // 64 KB
    unsigned long long* best = (unsigned long long*)(zn + 16384);  // 128 KB
    unsigned* gcnt = (unsigned*)(best + 16384);                    // 1 KB
    ushort* bucket = z16;                      // alias dead z16 (exactly 8 MB)

    k_cvt_z<<<dim3(256), dim3(256), 0, stream>>>(z, zf32, z16, zn);
    k_cvt_e<<<dim3(2048), dim3(256), 0, stream>>>(emb, e16, gcnt, loss);
    k_coarse<<<dim3(NROWS / 128, NCODES / 256), dim3(256), 0, stream>>>(z16, e16, tbl);
    k_flag<<<dim3(NROWS / 4), dim3(256), 0, stream>>>(tbl, bucket, gcnt, best);
    k_rescore2<<<dim3(256), dim3(256), 0, stream>>>(zf32, emb, zn, bucket, gcnt, best);
    k_gather<<<dim3(NROWS / 64), dim3(256), 0, stream>>>(z, emb, best, zq, oidx, loss);
}

// Round 10
// 268.177 us; speedup vs baseline: 4.2470x; 1.1027x over previous
//
#include <hip/hip_runtime.h>
#include <hip/hip_fp16.h>
#include <float.h>

#define K_DIM 256
#define HW1 1024
#define NROWS 16384
#define NCODES 8192

typedef __attribute__((ext_vector_type(8))) short bf16x8;
typedef __attribute__((ext_vector_type(4))) float f32x4;

__device__ __forceinline__ ushort bf16rn(float x) {
    unsigned u = __float_as_uint(x);
    return (ushort)((u + 0x7FFFu + ((u >> 16) & 1u)) >> 16);
}

__device__ __forceinline__ void gl16(const void* g, void* l) {
    __builtin_amdgcn_global_load_lds((const __attribute__((address_space(1))) void*)g,
                                     (__attribute__((address_space(3))) void*)l, 16, 0, 0);
}

// ---- kernel 1: z [b][k][hw] -> zf32/z16 [n][k] + FUSED exact znorm ----
__global__ __launch_bounds__(256) void k_cvt_z(const float* __restrict__ z,
                                               float* __restrict__ zf32,
                                               ushort* __restrict__ z16,
                                               float* __restrict__ zn) {
    __shared__ float ls[64 * 257];
    const int b = blockIdx.x >> 4, hw0 = (blockIdx.x & 15) * 64;
    const int t = threadIdx.x;
    const float* src = z + (size_t)b * 262144 + hw0;
#pragma unroll
    for (int i = 0; i < 16; ++i) {
        int f = t + i * 256;
        int kl = f >> 4, c4 = f & 15;
        float4 v = *(const float4*)(src + (size_t)kl * 1024 + c4 * 4);
        ls[(c4 * 4 + 0) * 257 + kl] = v.x;
        ls[(c4 * 4 + 1) * 257 + kl] = v.y;
        ls[(c4 * 4 + 2) * 257 + kl] = v.z;
        ls[(c4 * 4 + 3) * 257 + kl] = v.w;
    }
    __syncthreads();
    {
        const int w = t >> 6, cl = t & 63;
#pragma unroll
        for (int i = 0; i < 16; ++i) {
            int r = i * 4 + w;
            const float* lr = ls + r * 257;
            int n = b * 1024 + hw0 + r;
            float* od = zf32 + (size_t)n * 256;
            ushort* oh = z16 + (size_t)n * 256;
#pragma unroll
            for (int j = 0; j < 4; ++j) {
                float x = lr[cl + 64 * j];
                od[cl + 64 * j] = x;
                oh[cl + 64 * j] = bf16rn(x);
            }
        }
    }
    if (t < 64) {
        const int r = t;
        const float* lr = ls + r * 257;
        float half[2];
#pragma unroll
        for (int h = 0; h < 2; ++h) {
            float rj[8];
#pragma unroll
            for (int j = 0; j < 8; ++j) {
                float v = lr[h * 128 + j];
                float s = v * v;
                asm volatile("" : "+v"(s));
                rj[j] = s;
            }
#pragma unroll
            for (int i = 1; i < 16; ++i) {
#pragma unroll
                for (int j = 0; j < 8; ++j) {
                    float v = lr[h * 128 + 8 * i + j];
                    float s = v * v;
                    asm volatile("" : "+v"(s));
                    rj[j] += s;
                }
            }
            half[h] = ((rj[0] + rj[1]) + (rj[2] + rj[3])) +
                      ((rj[4] + rj[5]) + (rj[6] + rj[7]));
        }
        zn[b * 1024 + hw0 + r] = half[0] + half[1];
    }
}

// ---- kernel 2: emb fp32 -> bf16; block 0 also inits gcnt + loss ----
__global__ void k_cvt_e(const float* __restrict__ emb, ushort* __restrict__ e16,
                        unsigned* __restrict__ gcnt, float* __restrict__ loss) {
    if (blockIdx.x == 0) {
        gcnt[threadIdx.x] = 0u;
        if (threadIdx.x == 0) *loss = 0.f;
    }
    int f = blockIdx.x * 256 + threadIdx.x;
    float4 v = *(const float4*)(emb + (size_t)f * 4);
    ushort4 h;
    h.x = bf16rn(v.x); h.y = bf16rn(v.y); h.z = bf16rn(v.z); h.w = bf16rn(v.w);
    *(ushort4*)(e16 + (size_t)f * 4) = h;
}

// ---- kernel 3: bf16 MFMA coarse, tile 128x128 (round-8 main loop) with
// LDS transpose-reduce epilogue (no __shfl: shfl = ds_swizzle = LDS-pipe ops,
// 128/wave dominated the kernel in rounds 8/9) ----
__global__ __launch_bounds__(256) void k_coarse(
    const ushort* __restrict__ z16, const ushort* __restrict__ e16,
    ushort* __restrict__ tbl) {
    __shared__ char smem[35840];
    char* As = smem;                       // 16 KB (K-loop)
    char* Bs = smem + 16384;               // 16 KB (K-loop)
    float* parts = (float*)smem;           // epilogue: 512*17 f32 = 34816 B
    ushort* tb = (ushort*)(smem + 34816);  // 128*4 ushort = 1 KB
    const int tid = threadIdx.x;
    const int w = tid >> 6, lane = tid & 63;
    const int tx = lane & 15, q = lane >> 4;
    const int row0 = blockIdx.x * 128, c0 = blockIdx.y * 128;
    const int Am = (w & 1) * 64, Bn = (w >> 1) * 64;

    f32x4 acc[4][4];
#pragma unroll
    for (int mi = 0; mi < 4; ++mi)
#pragma unroll
        for (int ni = 0; ni < 4; ++ni) acc[mi][ni] = (f32x4){0.f, 0.f, 0.f, 0.f};

    for (int k0 = 0; k0 < K_DIM; k0 += 64) {
#pragma unroll
        for (int j = 0; j < 4; ++j) {
            int r = (w * 4 + j) * 8 + (lane >> 3);
            int c = (lane & 7) ^ (r & 7);  // inverse swizzle on global side
            gl16(z16 + (((size_t)(row0 + r)) << 8) + k0 + (c << 3),
                 As + (w * 4 + j) * 1024);
            gl16(e16 + (((size_t)(c0 + r)) << 8) + k0 + (c << 3),
                 Bs + (w * 4 + j) * 1024);
        }
        __syncthreads();
#pragma unroll
        for (int ks = 0; ks < 2; ++ks) {
            int cd = ks * 4;
            bf16x8 af[4], bfv[4];
#pragma unroll
            for (int mi = 0; mi < 4; ++mi)
                af[mi] = *(const bf16x8*)(As + (Am + mi * 16 + tx) * 128 +
                                          (((cd + q) ^ (tx & 7)) << 4));
#pragma unroll
            for (int ni = 0; ni < 4; ++ni)
                bfv[ni] = *(const bf16x8*)(Bs + (Bn + ni * 16 + tx) * 128 +
                                           (((cd + q) ^ (tx & 7)) << 4));
#pragma unroll
            for (int mi = 0; mi < 4; ++mi)
#pragma unroll
                for (int ni = 0; ni < 4; ++ni)
                    acc[mi][ni] = __builtin_amdgcn_mfma_f32_16x16x32_bf16(
                        af[mi], bfv[ni], acc[mi][ni], 0, 0, 0);
        }
        __syncthreads();  // final instance also protects parts-overlay of As/Bs
    }

    // epilogue phase 1: combine ni-pairs (VALU) and scatter partials to LDS
#pragma unroll
    for (int g = 0; g < 2; ++g) {
        int gb = (w >> 1) * 2 + g;  // block-local group 0..3
#pragma unroll
        for (int mi = 0; mi < 4; ++mi) {
#pragma unroll
            for (int e = 0; e < 4; ++e) {
                float pm = fmaxf(acc[mi][2 * g][e], acc[mi][2 * g + 1][e]);
                int row = Am + mi * 16 + q * 4 + e;
                parts[(gb * 128 + row) * 17 + tx] = pm;
            }
        }
    }
    __syncthreads();
    // phase 2: each thread reduces 16 partials for 2 (group,row) results
#pragma unroll
    for (int r2 = 0; r2 < 2; ++r2) {
        int p = tid * 2 + r2;  // 0..511 = gb*128 + row
        const float* pr = parts + p * 17;
        float f0 = fmaxf(pr[0], pr[1]), f1 = fmaxf(pr[2], pr[3]);
        float f2 = fmaxf(pr[4], pr[5]), f3 = fmaxf(pr[6], pr[7]);
        float f4 = fmaxf(pr[8], pr[9]), f5 = fmaxf(pr[10], pr[11]);
        float f6 = fmaxf(pr[12], pr[13]), f7 = fmaxf(pr[14], pr[15]);
        float m = fmaxf(fmaxf(fmaxf(f0, f1), fmaxf(f2, f3)),
                        fmaxf(fmaxf(f4, f5), fmaxf(f6, f7)));
        tb[(p & 127) * 4 + (p >> 7)] = __half_as_ushort(__float2half(m));
    }
    __syncthreads();
    if (tid < 128) {
        ushort4 v = *(ushort4*)(tb + tid * 4);
        *(ushort4*)(tbl + (size_t)(row0 + tid) * 256 + blockIdx.y * 4) = v;
    }
}

// ---- kernel 4: flag pass — bucket rows by candidate group; init best ----
__global__ void k_flag(const ushort* __restrict__ tbl, ushort* __restrict__ bucket,
                       unsigned* __restrict__ gcnt,
                       unsigned long long* __restrict__ best) {
    const int wid = threadIdx.x >> 6, lane = threadIdx.x & 63;
    const int n = blockIdx.x * 4 + wid;
    if (lane == 0) best[n] = 0xFFFFFFFFFFFFFFFFull;
    ushort4 raw = *(const ushort4*)(tbl + (size_t)n * 256 + lane * 4);
    float gm[4];
    gm[0] = __half2float(__ushort_as_half(raw.x));
    gm[1] = __half2float(__ushort_as_half(raw.y));
    gm[2] = __half2float(__ushort_as_half(raw.z));
    gm[3] = __half2float(__ushort_as_half(raw.w));
    float gmax = fmaxf(fmaxf(gm[0], gm[1]), fmaxf(gm[2], gm[3]));
#pragma unroll
    for (int m = 1; m < 64; m <<= 1) gmax = fmaxf(gmax, __shfl_xor(gmax, m, 64));
    const float th = gmax - 1.0e-4f;
#pragma unroll
    for (int i = 0; i < 4; ++i) {
        if (gm[i] >= th) {
            int g = lane * 4 + i;
            unsigned pos = atomicAdd(&gcnt[g], 1u);
            bucket[(size_t)g * NROWS + pos] = (ushort)n;
        }
    }
}

// ---- kernel 5: exact rescore, one block per group ----
__global__ __launch_bounds__(256) void k_rescore2(
    const float* __restrict__ zf32, const float* __restrict__ emb,
    const float* __restrict__ zn, const ushort* __restrict__ bucket,
    const unsigned* __restrict__ gcnt, unsigned long long* __restrict__ best) {
    __shared__ float eg[32 * 257];
    __shared__ float zs[8][256];
    __shared__ ushort rid[8];
    __shared__ float arow[8];
    const int g = blockIdx.x;
    const int t = threadIdx.x;
#pragma unroll
    for (int i = 0; i < 8; ++i) {
        int f = t + i * 256;
        int c = f >> 6, k4 = f & 63;
        float4 v = *(const float4*)(emb + (size_t)(g * 32 + c) * 256 + k4 * 4);
        float* dst = eg + c * 257 + k4 * 4;
        dst[0] = v.x; dst[1] = v.y; dst[2] = v.z; dst[3] = v.w;
    }
    const int cnt = (int)gcnt[g];
    for (int base = 0; base < cnt; base += 8) {
        __syncthreads();
        if (t < 8) {
            int i = base + t;
            if (i < cnt) {
                ushort r = bucket[(size_t)g * NROWS + i];
                rid[t] = r;
                arow[t] = zn[r];
            } else {
                rid[t] = 0xFFFF;
            }
        }
        __syncthreads();
#pragma unroll
        for (int i = 0; i < 2; ++i) {
            int f = t + i * 256;
            int s = f >> 6, k4 = f & 63;
            if (rid[s] != 0xFFFF)
                *(float4*)(&zs[s][k4 * 4]) =
                    *(const float4*)(zf32 + (size_t)rid[s] * 256 + k4 * 4);
        }
        __syncthreads();
        const int lane = t & 63, w = t >> 6;
        const int slot = w * 2 + (lane >> 5);
        const int code = lane & 31;
        if (rid[slot] != 0xFFFF) {
            const float* zr = zs[slot];
            const float* er = eg + code * 257;
            float acc = 0.f;
#pragma unroll 8
            for (int k = 0; k < 256; ++k) acc = fmaf(zr[k], er[k], acc);
            float d = arow[slot] - 2.f * acc;
            unsigned fb = __float_as_uint(d);
            fb ^= (fb & 0x80000000u) ? 0xFFFFFFFFu : 0x80000000u;
            unsigned long long pk =
                ((unsigned long long)fb << 32) | (unsigned)(g * 32 + code);
#pragma unroll
            for (int m = 1; m < 32; m <<= 1) {
                unsigned long long o = __shfl_xor(pk, m, 64);
                if (o < pk) pk = o;
            }
            if ((lane & 31) == 0) atomicMin(&best[rid[slot]], pk);
        }
    }
}

// ---- kernel 6: gather z_q + loss + oidx, 1 atomic/block ----
__global__ __launch_bounds__(256) void k_gather(
    const float* __restrict__ z, const float* __restrict__ emb,
    const unsigned long long* __restrict__ best, float* __restrict__ zq,
    float* __restrict__ oidx, float* __restrict__ loss) {
    __shared__ float eg[64][257];
    __shared__ float lsum[4];
    const int t = threadIdx.x;
    const int n0 = blockIdx.x * 64;
    const int b = n0 >> 10, hw0 = n0 & 1023;
    {
        const int row = t >> 2;
        const int cbase = (t & 3) * 64;
        const int code = (int)(unsigned)(best[n0 + row] & 0xFFFFFFFFull);
        if ((t & 3) == 0) oidx[n0 + row] = (float)code;
        const float* er = emb + (size_t)code * 256 + cbase;
        float* dst = &eg[row][cbase];
#pragma unroll
        for (int i = 0; i < 16; ++i) {
            float4 v = *(const float4*)(er + i * 4);
            dst[i * 4 + 0] = v.x; dst[i * 4 + 1] = v.y;
            dst[i * 4 + 2] = v.z; dst[i * 4 + 3] = v.w;
        }
    }
    __syncthreads();
    const int w = t >> 6, lane = t & 63;
    float acc = 0.f;
    const size_t obase = (size_t)b * 262144 + hw0 + lane;
#pragma unroll 4
    for (int ci = 0; ci < 64; ++ci) {
        int c = w * 64 + ci;
        float e = eg[lane][c];
        size_t off = obase + (size_t)c * 1024;
        float zv = z[off];
        zq[off] = e;
        float d = e - zv;
        acc = fmaf(d, d, acc);
    }
#pragma unroll
    for (int m = 32; m; m >>= 1) acc += __shfl_xor(acc, m, 64);
    if (lane == 0) lsum[w] = acc;
    __syncthreads();
    if (t == 0) {
        float s = (lsum[0] + lsum[1]) + (lsum[2] + lsum[3]);
        atomicAdd(loss, s * (2.f / 4194304.f));
    }
}

extern "C" void kernel_launch(void* const* d_in, const int* in_sizes, int n_in,
                              void* d_out, int out_size, void* d_ws, size_t ws_size,
                              hipStream_t stream) {
    const float* z = (const float*)d_in[0];
    const float* emb = (const float*)d_in[1];
    float* out = (float*)d_out;
    float* zq = out;
    float* loss = out + 4194304;
    float* oidx = out + 4194305;
    float* zf32 = out;  // zq region doubles as transposed-z scratch until k_gather

    ushort* z16 = (ushort*)d_ws;               // 8 MB; dead after k_coarse
    ushort* e16 = z16 + 4194304;               // 4 MB
    ushort* tbl = e16 + 2097152;               // 8 MB [n][256] f16
    float* zn = (float*)(tbl + 4194304);       // 64 KB
    unsigned long long* best = (unsigned long long*)(zn + 16384);  // 128 KB
    unsigned* gcnt = (unsigned*)(best + 16384);                    // 1 KB
    ushort* bucket = z16;                      // alias dead z16 (exactly 8 MB)

    k_cvt_z<<<dim3(256), dim3(256), 0, stream>>>(z, zf32, z16, zn);
    k_cvt_e<<<dim3(2048), dim3(256), 0, stream>>>(emb, e16, gcnt, loss);
    k_coarse<<<dim3(NROWS / 128, NCODES / 128), dim3(256), 0, stream>>>(z16, e16, tbl);
    k_flag<<<dim3(NROWS / 4), dim3(256), 0, stream>>>(tbl, bucket, gcnt, best);
    k_rescore2<<<dim3(256), dim3(256), 0, stream>>>(zf32, emb, zn, bucket, gcnt, best);
    k_gather<<<dim3(NROWS / 64), dim3(256), 0, stream>>>(z, emb, best, zq, oidx, loss);
}

// Round 11
// 239.680 us; speedup vs baseline: 4.7520x; 1.1189x over previous
//
#include <hip/hip_runtime.h>
#include <hip/hip_fp16.h>
#include <float.h>

#define K_DIM 256
#define HW1 1024
#define NROWS 16384
#define NCODES 8192

typedef __attribute__((ext_vector_type(8))) short bf16x8;
typedef __attribute__((ext_vector_type(4))) float f32x4;

__device__ __forceinline__ ushort bf16rn(float x) {
    unsigned u = __float_as_uint(x);
    return (ushort)((u + 0x7FFFu + ((u >> 16) & 1u)) >> 16);
}

__device__ __forceinline__ void gl16(const void* g, void* l) {
    __builtin_amdgcn_global_load_lds((const __attribute__((address_space(1))) void*)g,
                                     (__attribute__((address_space(3))) void*)l, 16, 0, 0);
}

// ---- kernel 1: z [b][k][hw] -> zf32/z16 [n][k] + FUSED exact znorm ----
// Register-transposed 4x4 micro-tiles: every LDS op is b128 at float4-pitch 65
// (all phases bank-even). 512 blocks (32 hw rows each) = 2/CU.
__global__ __launch_bounds__(256) void k_cvt_z(const float* __restrict__ z,
                                               float* __restrict__ zf32,
                                               ushort* __restrict__ z16,
                                               float* __restrict__ zn) {
    __shared__ float ls[32 * 260];  // [hw][k], pitch 260 floats (65 float4)
    const int b = blockIdx.x >> 5, hw0 = (blockIdx.x & 31) * 32;
    const int t = threadIdx.x;
    const float* src = z + (size_t)b * 262144 + hw0;
    // stage: 2 micro-tiles (4k x 4hw) per thread, transpose in registers
#pragma unroll
    for (int i = 0; i < 2; ++i) {
        int m = t + i * 256;
        int kq = m >> 3, hq = m & 7;
        const float* s0 = src + (size_t)(kq * 4) * 1024 + hq * 4;
        float4 r0 = *(const float4*)(s0);
        float4 r1 = *(const float4*)(s0 + 1024);
        float4 r2 = *(const float4*)(s0 + 2048);
        float4 r3 = *(const float4*)(s0 + 3072);
        *(float4*)(ls + (hq * 4 + 0) * 260 + kq * 4) = make_float4(r0.x, r1.x, r2.x, r3.x);
        *(float4*)(ls + (hq * 4 + 1) * 260 + kq * 4) = make_float4(r0.y, r1.y, r2.y, r3.y);
        *(float4*)(ls + (hq * 4 + 2) * 260 + kq * 4) = make_float4(r0.z, r1.z, r2.z, r3.z);
        *(float4*)(ls + (hq * 4 + 3) * 260 + kq * 4) = make_float4(r0.w, r1.w, r2.w, r3.w);
    }
    __syncthreads();
    // write-out: b128 LDS read + float4/ushort4 stores
    {
        const int w = t >> 6, cl = t & 63;
#pragma unroll
        for (int i = 0; i < 8; ++i) {
            int r = i * 4 + w;
            float4 v = *(const float4*)(ls + r * 260 + cl * 4);
            int n = b * 1024 + hw0 + r;
            *(float4*)(zf32 + (size_t)n * 256 + cl * 4) = v;
            ushort4 h;
            h.x = bf16rn(v.x); h.y = bf16rn(v.y);
            h.z = bf16rn(v.z); h.w = bf16rn(v.w);
            *(ushort4*)(z16 + (size_t)n * 256 + cl * 4) = h;
        }
    }
    // fused znorm: numpy pairwise order, bit-identical op sequence (8 strided
    // accumulators, serial 16 terms each, fixed combine tree, no FMA fusion)
    if (t < 32) {
        const float* lr = ls + t * 260;
        float half[2];
#pragma unroll
        for (int h = 0; h < 2; ++h) {
            float rj[8];
            {
                float4 a = *(const float4*)(lr + h * 128);
                float4 b4 = *(const float4*)(lr + h * 128 + 4);
                float s;
                s = a.x * a.x; asm volatile("" : "+v"(s)); rj[0] = s;
                s = a.y * a.y; asm volatile("" : "+v"(s)); rj[1] = s;
                s = a.z * a.z; asm volatile("" : "+v"(s)); rj[2] = s;
                s = a.w * a.w; asm volatile("" : "+v"(s)); rj[3] = s;
                s = b4.x * b4.x; asm volatile("" : "+v"(s)); rj[4] = s;
                s = b4.y * b4.y; asm volatile("" : "+v"(s)); rj[5] = s;
                s = b4.z * b4.z; asm volatile("" : "+v"(s)); rj[6] = s;
                s = b4.w * b4.w; asm volatile("" : "+v"(s)); rj[7] = s;
            }
#pragma unroll
            for (int i = 1; i < 16; ++i) {
                float4 a = *(const float4*)(lr + h * 128 + 8 * i);
                float4 b4 = *(const float4*)(lr + h * 128 + 8 * i + 4);
                float s;
                s = a.x * a.x; asm volatile("" : "+v"(s)); rj[0] += s;
                s = a.y * a.y; asm volatile("" : "+v"(s)); rj[1] += s;
                s = a.z * a.z; asm volatile("" : "+v"(s)); rj[2] += s;
                s = a.w * a.w; asm volatile("" : "+v"(s)); rj[3] += s;
                s = b4.x * b4.x; asm volatile("" : "+v"(s)); rj[4] += s;
                s = b4.y * b4.y; asm volatile("" : "+v"(s)); rj[5] += s;
                s = b4.z * b4.z; asm volatile("" : "+v"(s)); rj[6] += s;
                s = b4.w * b4.w; asm volatile("" : "+v"(s)); rj[7] += s;
            }
            half[h] = ((rj[0] + rj[1]) + (rj[2] + rj[3])) +
                      ((rj[4] + rj[5]) + (rj[6] + rj[7]));
        }
        zn[b * 1024 + hw0 + t] = half[0] + half[1];
    }
}

// ---- kernel 2: emb fp32 -> bf16; block 0 also inits gcnt + loss ----
__global__ void k_cvt_e(const float* __restrict__ emb, ushort* __restrict__ e16,
                        unsigned* __restrict__ gcnt, float* __restrict__ loss) {
    if (blockIdx.x == 0) {
        gcnt[threadIdx.x] = 0u;
        if (threadIdx.x == 0) *loss = 0.f;
    }
    int f = blockIdx.x * 256 + threadIdx.x;
    float4 v = *(const float4*)(emb + (size_t)f * 4);
    ushort4 h;
    h.x = bf16rn(v.x); h.y = bf16rn(v.y); h.z = bf16rn(v.z); h.w = bf16rn(v.w);
    *(ushort4*)(e16 + (size_t)f * 4) = h;
}

// ---- kernel 3: bf16 MFMA coarse, 128x128, LDS transpose-reduce epilogue ----
__global__ __launch_bounds__(256) void k_coarse(
    const ushort* __restrict__ z16, const ushort* __restrict__ e16,
    ushort* __restrict__ tbl) {
    __shared__ char smem[35840];
    char* As = smem;
    char* Bs = smem + 16384;
    float* parts = (float*)smem;           // epilogue overlay: 512*17 f32
    ushort* tb = (ushort*)(smem + 34816);  // 128*4 ushort
    const int tid = threadIdx.x;
    const int w = tid >> 6, lane = tid & 63;
    const int tx = lane & 15, q = lane >> 4;
    const int row0 = blockIdx.x * 128, c0 = blockIdx.y * 128;
    const int Am = (w & 1) * 64, Bn = (w >> 1) * 64;

    f32x4 acc[4][4];
#pragma unroll
    for (int mi = 0; mi < 4; ++mi)
#pragma unroll
        for (int ni = 0; ni < 4; ++ni) acc[mi][ni] = (f32x4){0.f, 0.f, 0.f, 0.f};

    for (int k0 = 0; k0 < K_DIM; k0 += 64) {
#pragma unroll
        for (int j = 0; j < 4; ++j) {
            int r = (w * 4 + j) * 8 + (lane >> 3);
            int c = (lane & 7) ^ (r & 7);
            gl16(z16 + (((size_t)(row0 + r)) << 8) + k0 + (c << 3),
                 As + (w * 4 + j) * 1024);
            gl16(e16 + (((size_t)(c0 + r)) << 8) + k0 + (c << 3),
                 Bs + (w * 4 + j) * 1024);
        }
        __syncthreads();
#pragma unroll
        for (int ks = 0; ks < 2; ++ks) {
            int cd = ks * 4;
            bf16x8 af[4], bfv[4];
#pragma unroll
            for (int mi = 0; mi < 4; ++mi)
                af[mi] = *(const bf16x8*)(As + (Am + mi * 16 + tx) * 128 +
                                          (((cd + q) ^ (tx & 7)) << 4));
#pragma unroll
            for (int ni = 0; ni < 4; ++ni)
                bfv[ni] = *(const bf16x8*)(Bs + (Bn + ni * 16 + tx) * 128 +
                                           (((cd + q) ^ (tx & 7)) << 4));
#pragma unroll
            for (int mi = 0; mi < 4; ++mi)
#pragma unroll
                for (int ni = 0; ni < 4; ++ni)
                    acc[mi][ni] = __builtin_amdgcn_mfma_f32_16x16x32_bf16(
                        af[mi], bfv[ni], acc[mi][ni], 0, 0, 0);
        }
        __syncthreads();
    }

#pragma unroll
    for (int g = 0; g < 2; ++g) {
        int gb = (w >> 1) * 2 + g;
#pragma unroll
        for (int mi = 0; mi < 4; ++mi) {
#pragma unroll
            for (int e = 0; e < 4; ++e) {
                float pm = fmaxf(acc[mi][2 * g][e], acc[mi][2 * g + 1][e]);
                int row = Am + mi * 16 + q * 4 + e;
                parts[(gb * 128 + row) * 17 + tx] = pm;
            }
        }
    }
    __syncthreads();
#pragma unroll
    for (int r2 = 0; r2 < 2; ++r2) {
        int p = tid * 2 + r2;
        const float* pr = parts + p * 17;
        float f0 = fmaxf(pr[0], pr[1]), f1 = fmaxf(pr[2], pr[3]);
        float f2 = fmaxf(pr[4], pr[5]), f3 = fmaxf(pr[6], pr[7]);
        float f4 = fmaxf(pr[8], pr[9]), f5 = fmaxf(pr[10], pr[11]);
        float f6 = fmaxf(pr[12], pr[13]), f7 = fmaxf(pr[14], pr[15]);
        float m = fmaxf(fmaxf(fmaxf(f0, f1), fmaxf(f2, f3)),
                        fmaxf(fmaxf(f4, f5), fmaxf(f6, f7)));
        tb[(p & 127) * 4 + (p >> 7)] = __half_as_ushort(__float2half(m));
    }
    __syncthreads();
    if (tid < 128) {
        ushort4 v = *(ushort4*)(tb + tid * 4);
        *(ushort4*)(tbl + (size_t)(row0 + tid) * 256 + blockIdx.y * 4) = v;
    }
}

// ---- kernel 4: flag pass — bucket rows by candidate group; init best ----
__global__ void k_flag(const ushort* __restrict__ tbl, ushort* __restrict__ bucket,
                       unsigned* __restrict__ gcnt,
                       unsigned long long* __restrict__ best) {
    const int wid = threadIdx.x >> 6, lane = threadIdx.x & 63;
    const int n = blockIdx.x * 4 + wid;
    if (lane == 0) best[n] = 0xFFFFFFFFFFFFFFFFull;
    ushort4 raw = *(const ushort4*)(tbl + (size_t)n * 256 + lane * 4);
    float gm[4];
    gm[0] = __half2float(__ushort_as_half(raw.x));
    gm[1] = __half2float(__ushort_as_half(raw.y));
    gm[2] = __half2float(__ushort_as_half(raw.z));
    gm[3] = __half2float(__ushort_as_half(raw.w));
    float gmax = fmaxf(fmaxf(gm[0], gm[1]), fmaxf(gm[2], gm[3]));
#pragma unroll
    for (int m = 1; m < 64; m <<= 1) gmax = fmaxf(gmax, __shfl_xor(gmax, m, 64));
    const float th = gmax - 1.0e-4f;
#pragma unroll
    for (int i = 0; i < 4; ++i) {
        if (gm[i] >= th) {
            int g = lane * 4 + i;
            unsigned pos = atomicAdd(&gcnt[g], 1u);
            bucket[(size_t)g * NROWS + pos] = (ushort)n;
        }
    }
}

// ---- kernel 5: exact rescore; 4 blocks per group (interleaved 8-row batches).
// atomicMin is order-independent -> identical results to the 1-block version.
__global__ __launch_bounds__(256) void k_rescore2(
    const float* __restrict__ zf32, const float* __restrict__ emb,
    const float* __restrict__ zn, const ushort* __restrict__ bucket,
    const unsigned* __restrict__ gcnt, unsigned long long* __restrict__ best) {
    __shared__ float eg[32 * 257];
    __shared__ float zs[8][256];
    __shared__ ushort rid[8];
    __shared__ float arow[8];
    const int g = blockIdx.x >> 2;
    const int split = blockIdx.x & 3;
    const int t = threadIdx.x;
#pragma unroll
    for (int i = 0; i < 8; ++i) {
        int f = t + i * 256;
        int c = f >> 6, k4 = f & 63;
        float4 v = *(const float4*)(emb + (size_t)(g * 32 + c) * 256 + k4 * 4);
        float* dst = eg + c * 257 + k4 * 4;
        dst[0] = v.x; dst[1] = v.y; dst[2] = v.z; dst[3] = v.w;
    }
    const int cnt = (int)gcnt[g];
    for (int base = split * 8; base < cnt; base += 32) {
        __syncthreads();
        if (t < 8) {
            int i = base + t;
            if (i < cnt) {
                ushort r = bucket[(size_t)g * NROWS + i];
                rid[t] = r;
                arow[t] = zn[r];
            } else {
                rid[t] = 0xFFFF;
            }
        }
        __syncthreads();
#pragma unroll
        for (int i = 0; i < 2; ++i) {
            int f = t + i * 256;
            int s = f >> 6, k4 = f & 63;
            if (rid[s] != 0xFFFF)
                *(float4*)(&zs[s][k4 * 4]) =
                    *(const float4*)(zf32 + (size_t)rid[s] * 256 + k4 * 4);
        }
        __syncthreads();
        const int lane = t & 63, w = t >> 6;
        const int slot = w * 2 + (lane >> 5);
        const int code = lane & 31;
        if (rid[slot] != 0xFFFF) {
            const float* zr = zs[slot];
            const float* er = eg + code * 257;
            float acc = 0.f;
#pragma unroll 8
            for (int k = 0; k < 256; ++k) acc = fmaf(zr[k], er[k], acc);
            float d = arow[slot] - 2.f * acc;
            unsigned fb = __float_as_uint(d);
            fb ^= (fb & 0x80000000u) ? 0xFFFFFFFFu : 0x80000000u;
            unsigned long long pk =
                ((unsigned long long)fb << 32) | (unsigned)(g * 32 + code);
#pragma unroll
            for (int m = 1; m < 32; m <<= 1) {
                unsigned long long o = __shfl_xor(pk, m, 64);
                if (o < pk) pk = o;
            }
            if ((lane & 31) == 0) atomicMin(&best[rid[slot]], pk);
        }
    }
}

// ---- kernel 6: gather z_q + loss + oidx, 1 atomic/block ----
__global__ __launch_bounds__(256) void k_gather(
    const float* __restrict__ z, const float* __restrict__ emb,
    const unsigned long long* __restrict__ best, float* __restrict__ zq,
    float* __restrict__ oidx, float* __restrict__ loss) {
    __shared__ float eg[64][257];
    __shared__ float lsum[4];
    const int t = threadIdx.x;
    const int n0 = blockIdx.x * 64;
    const int b = n0 >> 10, hw0 = n0 & 1023;
    {
        const int row = t >> 2;
        const int cbase = (t & 3) * 64;
        const int code = (int)(unsigned)(best[n0 + row] & 0xFFFFFFFFull);
        if ((t & 3) == 0) oidx[n0 + row] = (float)code;
        const float* er = emb + (size_t)code * 256 + cbase;
        float* dst = &eg[row][cbase];
#pragma unroll
        for (int i = 0; i < 16; ++i) {
            float4 v = *(const float4*)(er + i * 4);
            dst[i * 4 + 0] = v.x; dst[i * 4 + 1] = v.y;
            dst[i * 4 + 2] = v.z; dst[i * 4 + 3] = v.w;
        }
    }
    __syncthreads();
    const int w = t >> 6, lane = t & 63;
    float acc = 0.f;
    const size_t obase = (size_t)b * 262144 + hw0 + lane;
#pragma unroll 4
    for (int ci = 0; ci < 64; ++ci) {
        int c = w * 64 + ci;
        float e = eg[lane][c];
        size_t off = obase + (size_t)c * 1024;
        float zv = z[off];
        zq[off] = e;
        float d = e - zv;
        acc = fmaf(d, d, acc);
    }
#pragma unroll
    for (int m = 32; m; m >>= 1) acc += __shfl_xor(acc, m, 64);
    if (lane == 0) lsum[w] = acc;
    __syncthreads();
    if (t == 0) {
        float s = (lsum[0] + lsum[1]) + (lsum[2] + lsum[3]);
        atomicAdd(loss, s * (2.f / 4194304.f));
    }
}

extern "C" void kernel_launch(void* const* d_in, const int* in_sizes, int n_in,
                              void* d_out, int out_size, void* d_ws, size_t ws_size,
                              hipStream_t stream) {
    const float* z = (const float*)d_in[0];
    const float* emb = (const float*)d_in[1];
    float* out = (float*)d_out;
    float* zq = out;
    float* loss = out + 4194304;
    float* oidx = out + 4194305;
    float* zf32 = out;  // zq region doubles as transposed-z scratch until k_gather

    ushort* z16 = (ushort*)d_ws;               // 8 MB; dead after k_coarse
    ushort* e16 = z16 + 4194304;               // 4 MB
    ushort* tbl = e16 + 2097152;               // 8 MB [n][256] f16
    float* zn = (float*)(tbl + 4194304);       // 64 KB
    unsigned long long* best = (unsigned long long*)(zn + 16384);  // 128 KB
    unsigned* gcnt = (unsigned*)(best + 16384);                    // 1 KB
    ushort* bucket = z16;                      // alias dead z16 (exactly 8 MB)

    k_cvt_z<<<dim3(512), dim3(256), 0, stream>>>(z, zf32, z16, zn);
    k_cvt_e<<<dim3(2048), dim3(256), 0, stream>>>(emb, e16, gcnt, loss);
    k_coarse<<<dim3(NROWS / 128, NCODES / 128), dim3(256), 0, stream>>>(z16, e16, tbl);
    k_flag<<<dim3(NROWS / 4), dim3(256), 0, stream>>>(tbl, bucket, gcnt, best);
    k_rescore2<<<dim3(1024), dim3(256), 0, stream>>>(zf32, emb, zn, bucket, gcnt, best);
    k_gather<<<dim3(NROWS / 64), dim3(256), 0, stream>>>(z, emb, best, zq, oidx, loss);
}

// Round 12
// 234.302 us; speedup vs baseline: 4.8610x; 1.0230x over previous
//
#include <hip/hip_runtime.h>
#include <hip/hip_fp16.h>
#include <float.h>

#define K_DIM 256
#define HW1 1024
#define NROWS 16384
#define NCODES 8192

typedef __attribute__((ext_vector_type(8))) short bf16x8;
typedef __attribute__((ext_vector_type(4))) float f32x4;

__device__ __forceinline__ ushort bf16rn(float x) {
    unsigned u = __float_as_uint(x);
    return (ushort)((u + 0x7FFFu + ((u >> 16) & 1u)) >> 16);
}

__device__ __forceinline__ void gl16(const void* g, void* l) {
    __builtin_amdgcn_global_load_lds((const __attribute__((address_space(1))) void*)g,
                                     (__attribute__((address_space(3))) void*)l, 16, 0, 0);
}

// ---- kernel 1: FUSED  z-transpose/convert/znorm  +  emb->bf16  ----
// blocks 0..511: z [b][k][hw] -> zf32/z16 [n][k] + exact numpy-order znorm.
// blocks 512..767: emb fp32 -> bf16 (block 512 inits gcnt/loss).
__global__ __launch_bounds__(256) void k_cvt(const float* __restrict__ z,
                                             float* __restrict__ zf32,
                                             ushort* __restrict__ z16,
                                             float* __restrict__ zn,
                                             const float* __restrict__ emb,
                                             ushort* __restrict__ e16,
                                             unsigned* __restrict__ gcnt,
                                             float* __restrict__ loss) {
    __shared__ float ls[32 * 260];
    const int blk = blockIdx.x;
    const int t = threadIdx.x;
    if (blk >= 512) {  // ---- emb convert part ----
        const int eb = blk - 512;
        if (eb == 0) {
            gcnt[t] = 0u;
            if (t == 0) *loss = 0.f;
        }
#pragma unroll
        for (int i = 0; i < 8; ++i) {
            int f4 = eb * 2048 + i * 256 + t;
            float4 v = *(const float4*)(emb + (size_t)f4 * 4);
            ushort4 h;
            h.x = bf16rn(v.x); h.y = bf16rn(v.y);
            h.z = bf16rn(v.z); h.w = bf16rn(v.w);
            *(ushort4*)(e16 + (size_t)f4 * 4) = h;
        }
        return;
    }
    // ---- z part: 32 hw rows per block ----
    const int b = blk >> 5, hw0 = (blk & 31) * 32;
    const float* src = z + (size_t)b * 262144 + hw0;
#pragma unroll
    for (int i = 0; i < 2; ++i) {
        int m = t + i * 256;
        int kq = m >> 3, hq = m & 7;
        const float* s0 = src + (size_t)(kq * 4) * 1024 + hq * 4;
        float4 r0 = *(const float4*)(s0);
        float4 r1 = *(const float4*)(s0 + 1024);
        float4 r2 = *(const float4*)(s0 + 2048);
        float4 r3 = *(const float4*)(s0 + 3072);
        *(float4*)(ls + (hq * 4 + 0) * 260 + kq * 4) = make_float4(r0.x, r1.x, r2.x, r3.x);
        *(float4*)(ls + (hq * 4 + 1) * 260 + kq * 4) = make_float4(r0.y, r1.y, r2.y, r3.y);
        *(float4*)(ls + (hq * 4 + 2) * 260 + kq * 4) = make_float4(r0.z, r1.z, r2.z, r3.z);
        *(float4*)(ls + (hq * 4 + 3) * 260 + kq * 4) = make_float4(r0.w, r1.w, r2.w, r3.w);
    }
    __syncthreads();
    {
        const int w = t >> 6, cl = t & 63;
#pragma unroll
        for (int i = 0; i < 8; ++i) {
            int r = i * 4 + w;
            float4 v = *(const float4*)(ls + r * 260 + cl * 4);
            int n = b * 1024 + hw0 + r;
            *(float4*)(zf32 + (size_t)n * 256 + cl * 4) = v;
            ushort4 h;
            h.x = bf16rn(v.x); h.y = bf16rn(v.y);
            h.z = bf16rn(v.z); h.w = bf16rn(v.w);
            *(ushort4*)(z16 + (size_t)n * 256 + cl * 4) = h;
        }
    }
    if (t < 32) {
        const float* lr = ls + t * 260;
        float half[2];
#pragma unroll
        for (int h = 0; h < 2; ++h) {
            float rj[8];
            {
                float4 a = *(const float4*)(lr + h * 128);
                float4 b4 = *(const float4*)(lr + h * 128 + 4);
                float s;
                s = a.x * a.x; asm volatile("" : "+v"(s)); rj[0] = s;
                s = a.y * a.y; asm volatile("" : "+v"(s)); rj[1] = s;
                s = a.z * a.z; asm volatile("" : "+v"(s)); rj[2] = s;
                s = a.w * a.w; asm volatile("" : "+v"(s)); rj[3] = s;
                s = b4.x * b4.x; asm volatile("" : "+v"(s)); rj[4] = s;
                s = b4.y * b4.y; asm volatile("" : "+v"(s)); rj[5] = s;
                s = b4.z * b4.z; asm volatile("" : "+v"(s)); rj[6] = s;
                s = b4.w * b4.w; asm volatile("" : "+v"(s)); rj[7] = s;
            }
#pragma unroll
            for (int i = 1; i < 16; ++i) {
                float4 a = *(const float4*)(lr + h * 128 + 8 * i);
                float4 b4 = *(const float4*)(lr + h * 128 + 8 * i + 4);
                float s;
                s = a.x * a.x; asm volatile("" : "+v"(s)); rj[0] += s;
                s = a.y * a.y; asm volatile("" : "+v"(s)); rj[1] += s;
                s = a.z * a.z; asm volatile("" : "+v"(s)); rj[2] += s;
                s = a.w * a.w; asm volatile("" : "+v"(s)); rj[3] += s;
                s = b4.x * b4.x; asm volatile("" : "+v"(s)); rj[4] += s;
                s = b4.y * b4.y; asm volatile("" : "+v"(s)); rj[5] += s;
                s = b4.z * b4.z; asm volatile("" : "+v"(s)); rj[6] += s;
                s = b4.w * b4.w; asm volatile("" : "+v"(s)); rj[7] += s;
            }
            half[h] = ((rj[0] + rj[1]) + (rj[2] + rj[3])) +
                      ((rj[4] + rj[5]) + (rj[6] + rj[7]));
        }
        zn[b * 1024 + hw0 + t] = half[0] + half[1];
    }
}

// ---- kernel 2: bf16 MFMA coarse, 128x128, LDS transpose-reduce epilogue ----
__global__ __launch_bounds__(256) void k_coarse(
    const ushort* __restrict__ z16, const ushort* __restrict__ e16,
    ushort* __restrict__ tbl) {
    __shared__ char smem[35840];
    char* As = smem;
    char* Bs = smem + 16384;
    float* parts = (float*)smem;           // epilogue overlay: 512*17 f32
    ushort* tb = (ushort*)(smem + 34816);  // 128*4 ushort
    const int tid = threadIdx.x;
    const int w = tid >> 6, lane = tid & 63;
    const int tx = lane & 15, q = lane >> 4;
    const int row0 = blockIdx.x * 128, c0 = blockIdx.y * 128;
    const int Am = (w & 1) * 64, Bn = (w >> 1) * 64;

    f32x4 acc[4][4];
#pragma unroll
    for (int mi = 0; mi < 4; ++mi)
#pragma unroll
        for (int ni = 0; ni < 4; ++ni) acc[mi][ni] = (f32x4){0.f, 0.f, 0.f, 0.f};

    for (int k0 = 0; k0 < K_DIM; k0 += 64) {
#pragma unroll
        for (int j = 0; j < 4; ++j) {
            int r = (w * 4 + j) * 8 + (lane >> 3);
            int c = (lane & 7) ^ (r & 7);
            gl16(z16 + (((size_t)(row0 + r)) << 8) + k0 + (c << 3),
                 As + (w * 4 + j) * 1024);
            gl16(e16 + (((size_t)(c0 + r)) << 8) + k0 + (c << 3),
                 Bs + (w * 4 + j) * 1024);
        }
        __syncthreads();
#pragma unroll
        for (int ks = 0; ks < 2; ++ks) {
            int cd = ks * 4;
            bf16x8 af[4], bfv[4];
#pragma unroll
            for (int mi = 0; mi < 4; ++mi)
                af[mi] = *(const bf16x8*)(As + (Am + mi * 16 + tx) * 128 +
                                          (((cd + q) ^ (tx & 7)) << 4));
#pragma unroll
            for (int ni = 0; ni < 4; ++ni)
                bfv[ni] = *(const bf16x8*)(Bs + (Bn + ni * 16 + tx) * 128 +
                                           (((cd + q) ^ (tx & 7)) << 4));
#pragma unroll
            for (int mi = 0; mi < 4; ++mi)
#pragma unroll
                for (int ni = 0; ni < 4; ++ni)
                    acc[mi][ni] = __builtin_amdgcn_mfma_f32_16x16x32_bf16(
                        af[mi], bfv[ni], acc[mi][ni], 0, 0, 0);
        }
        __syncthreads();
    }

#pragma unroll
    for (int g = 0; g < 2; ++g) {
        int gb = (w >> 1) * 2 + g;
#pragma unroll
        for (int mi = 0; mi < 4; ++mi) {
#pragma unroll
            for (int e = 0; e < 4; ++e) {
                float pm = fmaxf(acc[mi][2 * g][e], acc[mi][2 * g + 1][e]);
                int row = Am + mi * 16 + q * 4 + e;
                parts[(gb * 128 + row) * 17 + tx] = pm;
            }
        }
    }
    __syncthreads();
#pragma unroll
    for (int r2 = 0; r2 < 2; ++r2) {
        int p = tid * 2 + r2;
        const float* pr = parts + p * 17;
        float f0 = fmaxf(pr[0], pr[1]), f1 = fmaxf(pr[2], pr[3]);
        float f2 = fmaxf(pr[4], pr[5]), f3 = fmaxf(pr[6], pr[7]);
        float f4 = fmaxf(pr[8], pr[9]), f5 = fmaxf(pr[10], pr[11]);
        float f6 = fmaxf(pr[12], pr[13]), f7 = fmaxf(pr[14], pr[15]);
        float m = fmaxf(fmaxf(fmaxf(f0, f1), fmaxf(f2, f3)),
                        fmaxf(fmaxf(f4, f5), fmaxf(f6, f7)));
        tb[(p & 127) * 4 + (p >> 7)] = __half_as_ushort(__float2half(m));
    }
    __syncthreads();
    if (tid < 128) {
        ushort4 v = *(ushort4*)(tb + tid * 4);
        *(ushort4*)(tbl + (size_t)(row0 + tid) * 256 + blockIdx.y * 4) = v;
    }
}

// ---- kernel 3: flag pass — bucket rows by candidate group; init best ----
__global__ void k_flag(const ushort* __restrict__ tbl, ushort* __restrict__ bucket,
                       unsigned* __restrict__ gcnt,
                       unsigned long long* __restrict__ best) {
    const int wid = threadIdx.x >> 6, lane = threadIdx.x & 63;
    const int n = blockIdx.x * 4 + wid;
    if (lane == 0) best[n] = 0xFFFFFFFFFFFFFFFFull;
    ushort4 raw = *(const ushort4*)(tbl + (size_t)n * 256 + lane * 4);
    float gm[4];
    gm[0] = __half2float(__ushort_as_half(raw.x));
    gm[1] = __half2float(__ushort_as_half(raw.y));
    gm[2] = __half2float(__ushort_as_half(raw.z));
    gm[3] = __half2float(__ushort_as_half(raw.w));
    float gmax = fmaxf(fmaxf(gm[0], gm[1]), fmaxf(gm[2], gm[3]));
#pragma unroll
    for (int m = 1; m < 64; m <<= 1) gmax = fmaxf(gmax, __shfl_xor(gmax, m, 64));
    const float th = gmax - 1.0e-4f;
#pragma unroll
    for (int i = 0; i < 4; ++i) {
        if (gm[i] >= th) {
            int g = lane * 4 + i;
            unsigned pos = atomicAdd(&gcnt[g], 1u);
            bucket[(size_t)g * NROWS + pos] = (ushort)n;
        }
    }
}

// ---- kernel 4: exact rescore; 4 blocks per group (order-independent) ----
__global__ __launch_bounds__(256) void k_rescore2(
    const float* __restrict__ zf32, const float* __restrict__ emb,
    const float* __restrict__ zn, const ushort* __restrict__ bucket,
    const unsigned* __restrict__ gcnt, unsigned long long* __restrict__ best) {
    __shared__ float eg[32 * 257];
    __shared__ float zs[8][256];
    __shared__ ushort rid[8];
    __shared__ float arow[8];
    const int g = blockIdx.x >> 2;
    const int split = blockIdx.x & 3;
    const int t = threadIdx.x;
#pragma unroll
    for (int i = 0; i < 8; ++i) {
        int f = t + i * 256;
        int c = f >> 6, k4 = f & 63;
        float4 v = *(const float4*)(emb + (size_t)(g * 32 + c) * 256 + k4 * 4);
        float* dst = eg + c * 257 + k4 * 4;
        dst[0] = v.x; dst[1] = v.y; dst[2] = v.z; dst[3] = v.w;
    }
    const int cnt = (int)gcnt[g];
    for (int base = split * 8; base < cnt; base += 32) {
        __syncthreads();
        if (t < 8) {
            int i = base + t;
            if (i < cnt) {
                ushort r = bucket[(size_t)g * NROWS + i];
                rid[t] = r;
                arow[t] = zn[r];
            } else {
                rid[t] = 0xFFFF;
            }
        }
        __syncthreads();
#pragma unroll
        for (int i = 0; i < 2; ++i) {
            int f = t + i * 256;
            int s = f >> 6, k4 = f & 63;
            if (rid[s] != 0xFFFF)
                *(float4*)(&zs[s][k4 * 4]) =
                    *(const float4*)(zf32 + (size_t)rid[s] * 256 + k4 * 4);
        }
        __syncthreads();
        const int lane = t & 63, w = t >> 6;
        const int slot = w * 2 + (lane >> 5);
        const int code = lane & 31;
        if (rid[slot] != 0xFFFF) {
            const float* zr = zs[slot];
            const float* er = eg + code * 257;
            float acc = 0.f;
#pragma unroll 8
            for (int k = 0; k < 256; ++k) acc = fmaf(zr[k], er[k], acc);
            float d = arow[slot] - 2.f * acc;
            unsigned fb = __float_as_uint(d);
            fb ^= (fb & 0x80000000u) ? 0xFFFFFFFFu : 0x80000000u;
            unsigned long long pk =
                ((unsigned long long)fb << 32) | (unsigned)(g * 32 + code);
#pragma unroll
            for (int m = 1; m < 32; m <<= 1) {
                unsigned long long o = __shfl_xor(pk, m, 64);
                if (o < pk) pk = o;
            }
            if ((lane & 31) == 0) atomicMin(&best[rid[slot]], pk);
        }
    }
}

// ---- kernel 5: gather z_q + loss + oidx; 32 rows/block, float4-across-hw ----
__global__ __launch_bounds__(256) void k_gather(
    const float* __restrict__ z, const float* __restrict__ emb,
    const unsigned long long* __restrict__ best, float* __restrict__ zq,
    float* __restrict__ oidx, float* __restrict__ loss) {
    __shared__ float eg[32 * 65];  // [row][c-chunk], pitch 65: all phases <=2-way
    __shared__ float lsum[4];
    const int t = threadIdx.x;
    const int n0 = blockIdx.x * 32;
    const int b = n0 >> 10, hw0 = n0 & 1023;
    {
        const int row = t & 31, p = t >> 5;  // 8 staging threads per row
        const int code = (int)(unsigned)(best[n0 + row] & 0xFFFFFFFFull);
        if (p == 0) oidx[n0 + row] = (float)code;
        const float* er = emb + (size_t)code * 256 + p * 32;
        float* dst = eg + row * 65 + p * 32;
#pragma unroll
        for (int i = 0; i < 8; ++i)
            *(float4*)(dst + i * 4) = *(const float4*)(er + i * 4);
    }
    __syncthreads();
    const int w = t >> 6, lane = t & 63;
    const int csub = lane >> 3, hwq = lane & 7;  // 8 channels x 8 hw-quads
    float acc = 0.f;
    const size_t zb = (size_t)b * 262144 + hw0 + hwq * 4;
#pragma unroll 2
    for (int it = 0; it < 8; ++it) {
        int c = w * 64 + it * 8 + csub;
        size_t off = zb + (size_t)c * 1024;
        float4 zv = *(const float4*)(z + off);
        int r = hwq * 4;
        float4 ev = make_float4(eg[(r + 0) * 65 + c], eg[(r + 1) * 65 + c],
                                eg[(r + 2) * 65 + c], eg[(r + 3) * 65 + c]);
        *(float4*)(zq + off) = ev;
        float d0 = ev.x - zv.x, d1 = ev.y - zv.y;
        float d2 = ev.z - zv.z, d3 = ev.w - zv.w;
        acc += d0 * d0 + d1 * d1 + d2 * d2 + d3 * d3;
    }
#pragma unroll
    for (int m = 32; m; m >>= 1) acc += __shfl_xor(acc, m, 64);
    if (lane == 0) lsum[w] = acc;
    __syncthreads();
    if (t == 0) {
        float s = (lsum[0] + lsum[1]) + (lsum[2] + lsum[3]);
        atomicAdd(loss, s * (2.f / 4194304.f));
    }
}

extern "C" void kernel_launch(void* const* d_in, const int* in_sizes, int n_in,
                              void* d_out, int out_size, void* d_ws, size_t ws_size,
                              hipStream_t stream) {
    const float* z = (const float*)d_in[0];
    const float* emb = (const float*)d_in[1];
    float* out = (float*)d_out;
    float* zq = out;
    float* loss = out + 4194304;
    float* oidx = out + 4194305;
    float* zf32 = out;  // zq region doubles as transposed-z scratch until k_gather

    ushort* z16 = (ushort*)d_ws;               // 8 MB; dead after k_coarse
    ushort* e16 = z16 + 4194304;               // 4 MB
    ushort* tbl = e16 + 2097152;               // 8 MB [n][256] f16
    float* zn = (float*)(tbl + 4194304);       // 64 KB
    unsigned long long* best = (unsigned long long*)(zn + 16384);  // 128 KB
    unsigned* gcnt = (unsigned*)(best + 16384);                    // 1 KB
    ushort* bucket = z16;                      // alias dead z16 (exactly 8 MB)

    k_cvt<<<dim3(768), dim3(256), 0, stream>>>(z, zf32, z16, zn, emb, e16, gcnt, loss);
    k_coarse<<<dim3(NROWS / 128, NCODES / 128), dim3(256), 0, stream>>>(z16, e16, tbl);
    k_flag<<<dim3(NROWS / 4), dim3(256), 0, stream>>>(tbl, bucket, gcnt, best);
    k_rescore2<<<dim3(1024), dim3(256), 0, stream>>>(zf32, emb, zn, bucket, gcnt, best);
    k_gather<<<dim3(NROWS / 32), dim3(256), 0, stream>>>(z, emb, best, zq, oidx, loss);
}